// Round 1
// baseline (12221.542 us; speedup 1.0000x reference)
//
#include <hip/hip_runtime.h>
#include <hip/hip_bf16.h>
#include <math.h>

#ifndef M_PI
#define M_PI 3.14159265358979323846
#endif

#define B_    1024
#define SX    180
#define SY    130
#define NC    3
#define IMG   (SX*SY)      // 23400
#define FLATK 70200
#define HID1  2808
#define NOUT  180
#define XROW  131
#define H1STR 2816

typedef __attribute__((ext_vector_type(8))) short short8;
typedef __attribute__((ext_vector_type(4))) float f32x4;

__device__ __forceinline__ unsigned short f2bf(float f){
  __hip_bfloat16 h = __float2bfloat16(f);
  return __builtin_bit_cast(unsigned short, h);
}

// ---------------- twiddle tables (double-precision trig, tiny) ----------------
__global__ void k_tables(float* __restrict__ cFy, float* __restrict__ sFy,
                         float* __restrict__ cFx, float* __restrict__ sFx){
  int i = blockIdx.x*256 + threadIdx.x;
  if (i < 16*SY){
    int ky = i / SY, y = i % SY;
    double ang = 2.0*M_PI*(double)((ky*y) % SY)/(double)SY;
    cFy[i] = (float)cos(ang); sFy[i] = (float)sin(ang);
  }
  if (i < 32*SX){
    int kxi = i / SX, x = i % SX;
    int kx = (kxi < 16) ? kxi : (kxi + 148);   // kx = 164..179 for upper block
    double ang = 2.0*M_PI*(double)((kx*x) % SX)/(double)SX;
    cFx[i] = (float)cos(ang); sFx[i] = (float)sin(ang);
  }
}

// ---------------- build h = [x, gridx, gridy] ----------------
__global__ void k_build(const float* __restrict__ xin, float* __restrict__ A){
  int b = blockIdx.y;
  int i = blockIdx.x*256 + threadIdx.x;
  if (i >= IMG) return;
  int x = i / SY, y = i - x*SY;
  float v = xin[(size_t)b*SX*XROW + x*XROW + y];
  size_t base = (size_t)b*NC*IMG;
  A[base + i]         = v;
  A[base + IMG + i]   = (float)x * (1.0f/179.0f);
  A[base + 2*IMG + i] = (float)y * (1.0f/129.0f);
}

// ---------------- instance-norm stats per (b,c) ----------------
__global__ void k_stats(const float* __restrict__ A, float* __restrict__ st){
  int bc = blockIdx.x;
  const float* p = A + (size_t)bc*IMG;
  float s = 0.f, ss = 0.f;
  for (int i = threadIdx.x; i < IMG; i += 256){ float v = p[i]; s += v; ss += v*v; }
  for (int o = 32; o >= 1; o >>= 1){ s += __shfl_down(s, o); ss += __shfl_down(ss, o); }
  __shared__ float sh[2][4];
  int wid = threadIdx.x >> 6, lane = threadIdx.x & 63;
  if (lane == 0){ sh[0][wid] = s; sh[1][wid] = ss; }
  __syncthreads();
  if (threadIdx.x == 0){
    s  = sh[0][0]+sh[0][1]+sh[0][2]+sh[0][3];
    ss = sh[1][0]+sh[1][1]+sh[1][2]+sh[1][3];
    float mean = s * (1.0f/IMG);
    float var  = ss * (1.0f/IMG) - mean*mean;
    st[bc*2]   = mean;
    st[bc*2+1] = rsqrtf(var + 1e-5f);
  }
}

// ---------------- apply norm (optionally + exact gelu), in place ----------------
template<int GELU>
__global__ void k_norm(float* __restrict__ A, const float* __restrict__ st){
  int bc = blockIdx.y;
  int i = blockIdx.x*256 + threadIdx.x;
  if (i >= IMG) return;
  float mean = st[bc*2], istd = st[bc*2+1];
  size_t idx = (size_t)bc*IMG + i;
  float v = (A[idx] - mean) * istd;
  if (GELU) v = 0.5f * v * (1.0f + erff(v * 0.70710678118654752f));
  A[idx] = v;
}

// ---------------- forward y-DFT: (b,c,x) row of 130 -> 16 complex ----------------
__global__ void k_fwd_y(const float* __restrict__ A,
                        const float* __restrict__ cFy, const float* __restrict__ sFy,
                        float* __restrict__ Yre, float* __restrict__ Yim){
  int wid = blockIdx.x*4 + (threadIdx.x >> 6);   // over B*NC*SX
  int lane = threadIdx.x & 63;
  int ky = lane & 15, qu = lane >> 4;
  const float* row = A + (size_t)wid*SY;
  float cr = 0.f, si = 0.f;
  for (int y = qu; y < SY; y += 4){
    float h = row[y];
    cr += h * cFy[ky*SY + y];
    si += h * sFy[ky*SY + y];
  }
  cr += __shfl_xor(cr, 16); si += __shfl_xor(si, 16);
  cr += __shfl_xor(cr, 32); si += __shfl_xor(si, 32);
  if (qu == 0){ Yre[(size_t)wid*16 + ky] = cr; Yim[(size_t)wid*16 + ky] = -si; }
}

// ---------------- forward x-DFT: 180 complex -> 32 kept kx ----------------
__global__ void k_fwd_x(const float* __restrict__ Yre, const float* __restrict__ Yim,
                        const float* __restrict__ cFx, const float* __restrict__ sFx,
                        float* __restrict__ Zre, float* __restrict__ Zim){
  int wid = blockIdx.x*4 + (threadIdx.x >> 6);   // over B*NC*16
  int lane = threadIdx.x & 63;
  int kxi = lane & 31, half = lane >> 5;
  int ky = wid & 15; int bc = wid >> 4;
  const float* yr = Yre + (size_t)bc*SX*16 + ky;
  const float* yi = Yim + (size_t)bc*SX*16 + ky;
  float zr = 0.f, zi = 0.f;
  for (int x = half; x < SX; x += 2){
    float Yr = yr[(size_t)x*16], Yi = yi[(size_t)x*16];
    float c = cFx[kxi*SX + x], s = sFx[kxi*SX + x];
    zr += Yr*c + Yi*s;      // * e^{-i phi}
    zi += Yi*c - Yr*s;
  }
  zr += __shfl_xor(zr, 32); zi += __shfl_xor(zi, 32);
  if (half == 0){
    size_t o = ((size_t)bc*32 + kxi)*16 + ky;
    Zre[o] = zr; Zim[o] = zi;
  }
}

// ---------------- channel mix (3x3 complex per mode) ----------------
__global__ void k_mix(const float* __restrict__ Zre, const float* __restrict__ Zim,
                      const float* __restrict__ w1, const float* __restrict__ w2,
                      float* __restrict__ Z2r, float* __restrict__ Z2i){
  int idx = blockIdx.x*256 + threadIdx.x;        // ((b*3+o)*32+kxi)*16+ky
  if (idx >= B_*NC*32*16) return;
  int ky = idx & 15;
  int kxi = (idx >> 4) & 31;
  int bo = idx >> 9;                              // b*3+o
  int o = bo % 3, b = bo / 3;
  const float* w = (kxi < 16) ? w1 : w2;
  int kxm = kxi & 15;
  float ar = 0.f, ai = 0.f;
  #pragma unroll
  for (int i = 0; i < 3; i++){
    size_t zo = (((size_t)b*3 + i)*32 + kxi)*16 + ky;
    float zr = Zre[zo], zi = Zim[zo];
    size_t wo = ((((size_t)i*3 + o)*16 + kxm)*16 + ky)*2;
    float wr = w[wo], wi = w[wo+1];
    ar += zr*wr - zi*wi;
    ai += zr*wi + zi*wr;
  }
  Z2r[idx] = ar; Z2i[idx] = ai;
}

// ---------------- inverse x-DFT: 32 kept kx -> 180 x ----------------
__global__ void k_inv_x(const float* __restrict__ Z2r, const float* __restrict__ Z2i,
                        const float* __restrict__ cFx, const float* __restrict__ sFx,
                        float* __restrict__ Gre, float* __restrict__ Gim){
  int idx = blockIdx.x*256 + threadIdx.x;        // ((b*3+o)*180+x)*16+ky
  if (idx >= B_*NC*SX*16) return;
  int ky = idx & 15;
  int x = (idx >> 4) % SX;
  int bo = idx / (SX*16);
  float gr = 0.f, gi = 0.f;
  #pragma unroll
  for (int kxi = 0; kxi < 32; kxi++){
    size_t zo = ((size_t)bo*32 + kxi)*16 + ky;
    float zr = Z2r[zo], zi = Z2i[zo];
    float c = cFx[kxi*SX + x], s = sFx[kxi*SX + x];
    gr += zr*c - zi*s;      // * e^{+i phi}
    gi += zr*s + zi*c;
  }
  Gre[idx] = gr * (1.0f/SX);
  Gim[idx] = gi * (1.0f/SX);
}

// ---------------- inverse y (c2r; DC-bin imaginary part IGNORED, pocketfft) ----------------
__global__ void k_inv_y(const float* __restrict__ Gre, const float* __restrict__ Gim,
                        const float* __restrict__ cFy, const float* __restrict__ sFy,
                        float* __restrict__ A){
  int bo = blockIdx.y;
  int i = blockIdx.x*256 + threadIdx.x;
  if (i >= IMG) return;
  int x = i / SY, y = i - x*SY;
  const float* gr = Gre + ((size_t)bo*SX + x)*16;
  const float* gi = Gim + ((size_t)bo*SX + x)*16;
  float acc = gr[0];                              // Re(G[x,0]) only
  #pragma unroll
  for (int ky = 1; ky < 16; ky++){
    acc += 2.0f * (gr[ky]*cFy[ky*SY + y] - gi[ky]*sFy[ky*SY + y]);
  }
  A[(size_t)bo*IMG + i] = acc * (1.0f/SY);
}

// ---------------- big GEMM: h(1024,70200) @ W^T(70200,2808), bf16 MFMA, +bias, relu ----------------
__global__ __launch_bounds__(256) void k_gemm1(const float* __restrict__ Abuf,
                                               const float* __restrict__ W,
                                               const float* __restrict__ bias,
                                               float* __restrict__ h1){
  __shared__ unsigned short As[64][40];   // stride 40 bf16 = 80B: 16B-aligned rows, 2-way banks (free)
  __shared__ unsigned short Bs[64][40];
  int t = threadIdx.x;
  int bx = blockIdx.x, by = blockIdx.y;
  int r0 = t >> 3;            // 0..31
  int kc = (t & 7) * 4;       // 0..28
  int wv = t >> 6, lane = t & 63, lr = lane & 15, lq = lane >> 4;
  f32x4 acc[4] = {};
  const int KSTEPS = 2194;    // ceil(70200/32): tail zero-padded
  for (int ks = 0; ks < KSTEPS; ks++){
    int gk = ks*32 + kc;
    bool kval = (gk < FLATK);         // 70200%4==0 so float4 fully valid or fully out
    #pragma unroll
    for (int rr = 0; rr < 2; rr++){
      int r = r0 + rr*32;
      float4 va = make_float4(0.f,0.f,0.f,0.f);
      if (kval) va = *(const float4*)&Abuf[(size_t)(bx*64 + r)*FLATK + gk];
      ushort4 ua; ua.x = f2bf(va.x); ua.y = f2bf(va.y); ua.z = f2bf(va.z); ua.w = f2bf(va.w);
      *(ushort4*)&As[r][kc] = ua;
      int gn = by*64 + r;
      float4 vb = make_float4(0.f,0.f,0.f,0.f);
      if (kval && gn < HID1) vb = *(const float4*)&W[(size_t)gn*FLATK + gk];
      ushort4 ub; ub.x = f2bf(vb.x); ub.y = f2bf(vb.y); ub.z = f2bf(vb.z); ub.w = f2bf(vb.w);
      *(ushort4*)&Bs[r][kc] = ub;
    }
    __syncthreads();
    // A frag: m = lane&15, k = (lane>>4)*8 + i (contiguous-8 hypothesis; flip to
    // two b64 halves [4*lq..+3] and [16+4*lq..+3] if absmax explodes)
    short8 a = *(const short8*)&As[wv*16 + lr][lq*8];
    #pragma unroll
    for (int j = 0; j < 4; j++){
      short8 b = *(const short8*)&Bs[j*16 + lr][lq*8];
      acc[j] = __builtin_amdgcn_mfma_f32_16x16x32_bf16(a, b, acc[j], 0, 0, 0);
    }
    __syncthreads();
  }
  // C/D: col = lane&15, row = (lane>>4)*4 + reg   [guide §3, m89-verified]
  #pragma unroll
  for (int j = 0; j < 4; j++){
    #pragma unroll
    for (int r = 0; r < 4; r++){
      int m = wv*16 + lq*4 + r;
      int n = j*16 + lr;
      int gn = by*64 + n;
      if (gn < HID1){
        int gb = bx*64 + m;
        float v = acc[j][r] + bias[gn];
        h1[(size_t)gb*H1STR + gn] = fmaxf(v, 0.0f);
      }
    }
  }
}

// ---------------- out1 layer 2: (1024,2808) @ (2808->180) + b2 (no relu) ----------------
__global__ __launch_bounds__(256) void k_gemm2(const float* __restrict__ h1,
                                               const float* __restrict__ w2,
                                               const float* __restrict__ b2,
                                               float* __restrict__ o1){
  __shared__ float hs[16][68];
  __shared__ float wsm[16][68];
  int t = threadIdx.x;
  int bx = blockIdx.x, by = blockIdx.y;
  int r = t >> 4, c4 = (t & 15) * 4;
  int bi = t >> 4, oi = t & 15;
  float acc = 0.f;
  for (int ks = 0; ks < 44; ks++){
    int gk = ks*64 + c4;
    float4 va = make_float4(0.f,0.f,0.f,0.f);
    if (gk < HID1) va = *(const float4*)&h1[(size_t)(bx*16 + r)*H1STR + gk];
    *(float4*)&hs[r][c4] = va;
    int go = by*16 + r;
    float4 vb = make_float4(0.f,0.f,0.f,0.f);
    if (gk < HID1 && go < NOUT) vb = *(const float4*)&w2[(size_t)go*HID1 + gk];
    *(float4*)&wsm[r][c4] = vb;
    __syncthreads();
    #pragma unroll 8
    for (int k = 0; k < 64; k++) acc += hs[bi][k] * wsm[oi][k];
    __syncthreads();
  }
  int go = by*16 + oi;
  if (go < NOUT) o1[(size_t)(bx*16 + bi)*NOUT + go] = acc + b2[go];
}

// ---------------- final: interleave with x0n, reg2 MLP, rescale ----------------
__global__ void k_reg2(const float* __restrict__ o1, const float* __restrict__ xin,
                       const float* __restrict__ w1, const float* __restrict__ b1,
                       const float* __restrict__ w2, const float* __restrict__ b2,
                       float* __restrict__ outp){
  __shared__ float s[360];
  __shared__ float tt[180];
  int b = blockIdx.x, t = threadIdx.x;
  if (t < 180){
    s[2*t]   = o1[b*NOUT + t];
    s[2*t+1] = (xin[(size_t)b*SX*XROW + t*XROW + (XROW-1)] - 400.0f) * 0.01f;
  }
  __syncthreads();
  if (t < 180){
    float a = b1[t];
    for (int j = 0; j < 360; j++) a += s[j] * w1[t*360 + j];
    tt[t] = fmaxf(a, 0.0f);
  }
  __syncthreads();
  if (t < 180){
    float a = b2[t];
    for (int j = 0; j < 180; j++) a += tt[j] * w2[t*180 + j];
    outp[b*NOUT + t] = a*100.0f + 400.0f;
  }
}

extern "C" void kernel_launch(void* const* d_in, const int* in_sizes, int n_in,
                              void* d_out, int out_size, void* d_ws, size_t ws_size,
                              hipStream_t stream){
  const float* xin   = (const float*)d_in[0];
  const float* wA[2] = {(const float*)d_in[1], (const float*)d_in[3]};
  const float* wB[2] = {(const float*)d_in[2], (const float*)d_in[4]};
  const float* o1w1  = (const float*)d_in[5];
  const float* o1b1  = (const float*)d_in[6];
  const float* o1w2  = (const float*)d_in[7];
  const float* o1b2  = (const float*)d_in[8];
  const float* r2w1  = (const float*)d_in[9];
  const float* r2b1  = (const float*)d_in[10];
  const float* r2w2  = (const float*)d_in[11];
  const float* r2b2  = (const float*)d_in[12];
  float* ws  = (float*)d_ws;
  float* out = (float*)d_out;

  // workspace layout (floats); total ~99M floats ~396 MB
  size_t oA   = 0;
  size_t oYre = oA   + (size_t)B_*NC*IMG;
  size_t oYim = oYre + (size_t)B_*NC*SX*16;
  size_t oZre = oYim + (size_t)B_*NC*SX*16;
  size_t oZim = oZre + (size_t)B_*NC*32*16;
  size_t oZ2r = oZim + (size_t)B_*NC*32*16;
  size_t oZ2i = oZ2r + (size_t)B_*NC*32*16;
  size_t oSt  = oZ2i + (size_t)B_*NC*32*16;
  size_t oH1  = oSt  + (size_t)B_*NC*2;
  size_t oO1  = oH1  + (size_t)B_*H1STR;
  size_t oCFy = oO1  + (size_t)B_*NOUT;
  size_t oSFy = oCFy + 16*SY;
  size_t oCFx = oSFy + 16*SY;
  size_t oSFx = oCFx + 32*SX;

  float *A = ws + oA, *Yre = ws + oYre, *Yim = ws + oYim;
  float *Zre = ws + oZre, *Zim = ws + oZim, *Z2r = ws + oZ2r, *Z2i = ws + oZ2i;
  float *St = ws + oSt, *H1 = ws + oH1, *O1 = ws + oO1;
  float *cFy = ws + oCFy, *sFy = ws + oSFy, *cFx = ws + oCFx, *sFx = ws + oSFx;

  k_tables<<<23, 256, 0, stream>>>(cFy, sFy, cFx, sFx);
  k_build<<<dim3(92, B_), 256, 0, stream>>>(xin, A);

  for (int L = 0; L < 2; L++){
    k_stats<<<B_*NC, 256, 0, stream>>>(A, St);
    k_norm<0><<<dim3(92, B_*NC), 256, 0, stream>>>(A, St);
    k_fwd_y<<<B_*NC*SX/4, 256, 0, stream>>>(A, cFy, sFy, Yre, Yim);
    k_fwd_x<<<B_*NC*16/4, 256, 0, stream>>>(Yre, Yim, cFx, sFx, Zre, Zim);
    k_mix<<<(B_*NC*32*16)/256, 256, 0, stream>>>(Zre, Zim, wA[L], wB[L], Z2r, Z2i);
    k_inv_x<<<(B_*NC*SX*16)/256, 256, 0, stream>>>(Z2r, Z2i, cFx, sFx, Yre, Yim);
    k_inv_y<<<dim3(92, B_*NC), 256, 0, stream>>>(Yre, Yim, cFy, sFy, A);
    k_stats<<<B_*NC, 256, 0, stream>>>(A, St);
    k_norm<1><<<dim3(92, B_*NC), 256, 0, stream>>>(A, St);
  }

  k_gemm1<<<dim3(16, 44), 256, 0, stream>>>(A, o1w1, o1b1, H1);
  k_gemm2<<<dim3(64, 12), 256, 0, stream>>>(H1, o1w2, o1b2, O1);
  k_reg2<<<B_, 192, 0, stream>>>(O1, xin, r2w1, r2b1, r2w2, r2b2, out);
}

// Round 2
// 6997.858 us; speedup vs baseline: 1.7465x; 1.7465x over previous
//
#include <hip/hip_runtime.h>
#include <hip/hip_bf16.h>
#include <math.h>

#ifndef M_PI
#define M_PI 3.14159265358979323846
#endif

#define B_    1024
#define SX    180
#define SY    130
#define NC    3
#define IMG   23400
#define FLATK 70200
#define KPAD  70208
#define HID1  2808
#define NOUT  180
#define XROW  131
#define H1STR 2816
#define KSTEPS 2194   // KPAD/32
#define KCH    549    // ceil(KSTEPS/4)

typedef __attribute__((ext_vector_type(8))) short short8;
typedef __attribute__((ext_vector_type(4))) float f32x4;
typedef __attribute__((address_space(3))) unsigned int lds_u32;
typedef __attribute__((address_space(1))) const unsigned int glb_u32;

__device__ __forceinline__ unsigned short f2bf(float f){
  __hip_bfloat16 h = __float2bfloat16(f);
  return __builtin_bit_cast(unsigned short, h);
}

__device__ __forceinline__ void gl_lds16(const void* g, void* l){
  __builtin_amdgcn_global_load_lds((glb_u32*)g, (lds_u32*)l, 16, 0, 0);
}

// ---------------- twiddle tables ----------------
__global__ void k_tables(float* __restrict__ cFy, float* __restrict__ sFy,
                         float* __restrict__ cFx, float* __restrict__ sFx){
  int i = blockIdx.x*256 + threadIdx.x;
  if (i < 16*SY){
    int ky = i / SY, y = i % SY;
    double ang = 2.0*M_PI*(double)((ky*y) % SY)/(double)SY;
    cFy[i] = (float)cos(ang); sFy[i] = (float)sin(ang);
  }
  if (i < 32*SX){
    int kxi = i / SX, x = i % SX;
    int kx = (kxi < 16) ? kxi : (kxi + 148);
    double ang = 2.0*M_PI*(double)((kx*x) % SX)/(double)SX;
    cFx[i] = (float)cos(ang); sFx[i] = (float)sin(ang);
  }
}

// ---------------- build h = [x, gridx, gridy] ----------------
__global__ void k_build(const float* __restrict__ xin, float* __restrict__ A){
  int b = blockIdx.y;
  int i = blockIdx.x*256 + threadIdx.x;
  if (i >= IMG) return;
  int x = i / SY, y = i - x*SY;
  float v = xin[(size_t)b*SX*XROW + x*XROW + y];
  size_t base = (size_t)b*NC*IMG;
  A[base + i]         = v;
  A[base + IMG + i]   = (float)x * (1.0f/179.0f);
  A[base + 2*IMG + i] = (float)y * (1.0f/129.0f);
}

// ---------------- fused instance-norm (stats + apply [+gelu] [+bf16 out]) ----------------
// one block per (b,c); pass1 reduces, pass2 applies (L2-hot re-read)
template<int GELU, int OUTBF>
__global__ __launch_bounds__(256) void k_statnorm(float* __restrict__ A,
                                                  unsigned short* __restrict__ Abf){
  int bc = blockIdx.x;
  float* p = A + (size_t)bc*IMG;
  float4* p4 = (float4*)p;
  float s = 0.f, ss = 0.f;
  for (int i = threadIdx.x; i < IMG/4; i += 256){
    float4 v = p4[i];
    s  += v.x+v.y+v.z+v.w;
    ss += v.x*v.x+v.y*v.y+v.z*v.z+v.w*v.w;
  }
  for (int o = 32; o >= 1; o >>= 1){ s += __shfl_down(s, o); ss += __shfl_down(ss, o); }
  __shared__ float sh[2][4];
  __shared__ float mb[2];
  int wid = threadIdx.x >> 6, ln = threadIdx.x & 63;
  if (ln == 0){ sh[0][wid] = s; sh[1][wid] = ss; }
  __syncthreads();
  if (threadIdx.x == 0){
    s  = sh[0][0]+sh[0][1]+sh[0][2]+sh[0][3];
    ss = sh[1][0]+sh[1][1]+sh[1][2]+sh[1][3];
    float mean = s * (1.0f/IMG);
    float var  = ss * (1.0f/IMG) - mean*mean;
    mb[0] = mean; mb[1] = rsqrtf(var + 1e-5f);
  }
  __syncthreads();
  float mean = mb[0], istd = mb[1];
  int b = bc/3, c = bc - b*3;
  for (int i = threadIdx.x; i < IMG/4; i += 256){
    float4 v = p4[i];
    float r[4] = {(v.x-mean)*istd, (v.y-mean)*istd, (v.z-mean)*istd, (v.w-mean)*istd};
    if (GELU){
      #pragma unroll
      for (int j = 0; j < 4; j++)
        r[j] = 0.5f * r[j] * (1.0f + erff(r[j] * 0.70710678118654752f));
    }
    if (OUTBF){
      ushort4 u; u.x = f2bf(r[0]); u.y = f2bf(r[1]); u.z = f2bf(r[2]); u.w = f2bf(r[3]);
      *(ushort4*)&Abf[(size_t)b*KPAD + c*IMG + i*4] = u;
    } else {
      p4[i] = make_float4(r[0], r[1], r[2], r[3]);
    }
  }
}

// ---------------- forward y-DFT ----------------
__global__ void k_fwd_y(const float* __restrict__ A,
                        const float* __restrict__ cFy, const float* __restrict__ sFy,
                        float* __restrict__ Yre, float* __restrict__ Yim){
  int wid = blockIdx.x*4 + (threadIdx.x >> 6);
  int lane = threadIdx.x & 63;
  int ky = lane & 15, qu = lane >> 4;
  const float* row = A + (size_t)wid*SY;
  float cr = 0.f, si = 0.f;
  #pragma unroll 4
  for (int y = qu; y < SY; y += 4){
    float h = row[y];
    cr += h * cFy[ky*SY + y];
    si += h * sFy[ky*SY + y];
  }
  cr += __shfl_xor(cr, 16); si += __shfl_xor(si, 16);
  cr += __shfl_xor(cr, 32); si += __shfl_xor(si, 32);
  if (qu == 0){ Yre[(size_t)wid*16 + ky] = cr; Yim[(size_t)wid*16 + ky] = -si; }
}

// ---------------- forward x-DFT: one block per (b,c), LDS-staged Y ----------------
__global__ __launch_bounds__(256) void k_fwd_x(const float* __restrict__ Yre, const float* __restrict__ Yim,
                                               const float* __restrict__ cFx, const float* __restrict__ sFx,
                                               float* __restrict__ Zre, float* __restrict__ Zim){
  int bc = blockIdx.x;
  __shared__ float Yr[SX*16], Yi[SX*16];
  {
    const float4* yr4 = (const float4*)(Yre + (size_t)bc*SX*16);
    const float4* yi4 = (const float4*)(Yim + (size_t)bc*SX*16);
    for (int i = threadIdx.x; i < SX*16/4; i += 256){
      *(float4*)&Yr[i*4] = yr4[i];
      *(float4*)&Yi[i*4] = yi4[i];
    }
  }
  __syncthreads();
  for (int o = threadIdx.x; o < 512; o += 256){
    int ky = o & 15, kxi = o >> 4;
    float zr = 0.f, zi = 0.f;
    #pragma unroll 4
    for (int x = 0; x < SX; x++){
      float Yrv = Yr[x*16+ky], Yiv = Yi[x*16+ky];
      float c = cFx[kxi*SX+x], s = sFx[kxi*SX+x];
      zr += Yrv*c + Yiv*s;
      zi += Yiv*c - Yrv*s;
    }
    size_t oo = (size_t)bc*512 + o;
    Zre[oo] = zr; Zim[oo] = zi;
  }
}

// ---------------- channel mix ----------------
__global__ void k_mix(const float* __restrict__ Zre, const float* __restrict__ Zim,
                      const float* __restrict__ w1, const float* __restrict__ w2,
                      float* __restrict__ Z2r, float* __restrict__ Z2i){
  int idx = blockIdx.x*256 + threadIdx.x;
  if (idx >= B_*NC*512) return;
  int ky = idx & 15;
  int kxi = (idx >> 4) & 31;
  int bo = idx >> 9;
  int o = bo % 3, b = bo / 3;
  const float* w = (kxi < 16) ? w1 : w2;
  int kxm = kxi & 15;
  float ar = 0.f, ai = 0.f;
  #pragma unroll
  for (int i = 0; i < 3; i++){
    size_t zo = (((size_t)b*3 + i)*32 + kxi)*16 + ky;
    float zr = Zre[zo], zi = Zim[zo];
    size_t wo = ((((size_t)i*3 + o)*16 + kxm)*16 + ky)*2;
    float wr = w[wo], wi = w[wo+1];
    ar += zr*wr - zi*wi;
    ai += zr*wi + zi*wr;
  }
  Z2r[idx] = ar; Z2i[idx] = ai;
}

// ---------------- inverse x-DFT: one block per (b,o), LDS-staged Z ----------------
__global__ __launch_bounds__(256) void k_inv_x(const float* __restrict__ Z2r, const float* __restrict__ Z2i,
                                               const float* __restrict__ cFx, const float* __restrict__ sFx,
                                               float* __restrict__ Gre, float* __restrict__ Gim){
  int bo = blockIdx.x;
  __shared__ float Zr[512], Zi[512];
  for (int i = threadIdx.x; i < 512; i += 256){
    Zr[i] = Z2r[(size_t)bo*512 + i];
    Zi[i] = Z2i[(size_t)bo*512 + i];
  }
  __syncthreads();
  for (int o = threadIdx.x; o < SX*16; o += 256){
    int ky = o & 15, x = o >> 4;
    float gr = 0.f, gi = 0.f;
    #pragma unroll
    for (int k = 0; k < 32; k++){
      float zr = Zr[k*16+ky], zi = Zi[k*16+ky];
      float c = cFx[k*SX+x], s = sFx[k*SX+x];
      gr += zr*c - zi*s;
      gi += zr*s + zi*c;
    }
    size_t oo = (size_t)bo*SX*16 + o;
    Gre[oo] = gr * (1.0f/SX);
    Gim[oo] = gi * (1.0f/SX);
  }
}

// ---------------- inverse y (c2r; ky=0 imaginary ignored) ----------------
__global__ void k_inv_y(const float* __restrict__ Gre, const float* __restrict__ Gim,
                        const float* __restrict__ cFy, const float* __restrict__ sFy,
                        float* __restrict__ A){
  int bo = blockIdx.y;
  int i = blockIdx.x*256 + threadIdx.x;
  if (i >= IMG) return;
  int x = i / SY, y = i - x*SY;
  const float* gr = Gre + ((size_t)bo*SX + x)*16;
  const float* gi = Gim + ((size_t)bo*SX + x)*16;
  float acc = gr[0];
  #pragma unroll
  for (int ky = 1; ky < 16; ky++){
    acc += 2.0f * (gr[ky]*cFy[ky*SY + y] - gi[ky]*sFy[ky*SY + y]);
  }
  A[(size_t)bo*IMG + i] = acc * (1.0f/SY);
}

// ---------------- W fp32 -> bf16 (padded to KPAD) ----------------
__global__ void k_cvt_w(const float* __restrict__ W, unsigned short* __restrict__ Wbf){
  int row = blockIdx.y;
  int gi = blockIdx.x*256 + threadIdx.x;       // group of 8 k's
  if (gi >= KPAD/8) return;
  unsigned short* dst = Wbf + (size_t)row*KPAD + gi*8;
  if (gi*8 >= FLATK){
    *(ushort4*)dst = make_ushort4(0,0,0,0);
    *(ushort4*)(dst+4) = make_ushort4(0,0,0,0);
    return;
  }
  const float4* src = (const float4*)(W + (size_t)row*FLATK + gi*8);
  float4 v0 = src[0], v1 = src[1];
  ushort4 u0, u1;
  u0.x=f2bf(v0.x); u0.y=f2bf(v0.y); u0.z=f2bf(v0.z); u0.w=f2bf(v0.w);
  u1.x=f2bf(v1.x); u1.y=f2bf(v1.y); u1.z=f2bf(v1.z); u1.w=f2bf(v1.w);
  *(ushort4*)dst = u0;
  *(ushort4*)(dst+4) = u1;
}

// ---------------- zero-pad A bf16 k-tail ----------------
__global__ void k_padA(unsigned short* __restrict__ Abf){
  int t = blockIdx.x*256 + threadIdx.x;
  if (t >= B_*2) return;
  int b = t >> 1, h = t & 1;
  *(ushort4*)&Abf[(size_t)b*KPAD + FLATK + h*4] = make_ushort4(0,0,0,0);
}

// ---------------- fast GEMM: 128x128 tile, BK=32, global_load_lds, split-K ----------------
__global__ __launch_bounds__(256) void k_gemm_fast(const unsigned short* __restrict__ Abf,
                                                   const unsigned short* __restrict__ Wbf,
                                                   float* __restrict__ Cpart){
  __shared__ unsigned short As[128*32];
  __shared__ unsigned short Bs[128*32];
  int t = threadIdx.x;
  int bx = blockIdx.x, by = blockIdx.y, kz = blockIdx.z;
  int ks0 = kz*KCH, ks1 = min(ks0 + KCH, KSTEPS);
  int lane = t & 63, wv = t >> 6;
  int lr = lane & 15, lq = lane >> 4;
  int wr = wv >> 1, wc = wv & 1;
  int srow = t >> 2, scol = (t & 3) * 8;     // staging: 64 rows x 4 slots of 8 bf16
  const unsigned short* ga0 = Abf + (size_t)(bx*128 + srow)*KPAD + scol;
  const unsigned short* ga1 = ga0 + (size_t)64*KPAD;
  int wrow0 = min(by*128 + srow, HID1-1);
  int wrow1 = min(by*128 + 64 + srow, HID1-1);
  const unsigned short* gb0 = Wbf + (size_t)wrow0*KPAD + scol;
  const unsigned short* gb1 = Wbf + (size_t)wrow1*KPAD + scol;
  unsigned short* la0 = &As[srow*32 + scol];
  unsigned short* la1 = &As[(64+srow)*32 + scol];
  unsigned short* lb0 = &Bs[srow*32 + scol];
  unsigned short* lb1 = &Bs[(64+srow)*32 + scol];
  f32x4 acc[4][4] = {};
  for (int ks = ks0; ks < ks1; ks++){
    size_t gk = (size_t)ks*32;
    gl_lds16(ga0 + gk, la0);
    gl_lds16(ga1 + gk, la1);
    gl_lds16(gb0 + gk, lb0);
    gl_lds16(gb1 + gk, lb1);
    __syncthreads();
    short8 a[4], b[4];
    #pragma unroll
    for (int m = 0; m < 4; m++)
      a[m] = *(const short8*)&As[(wr*64 + m*16 + lr)*32 + lq*8];
    #pragma unroll
    for (int n = 0; n < 4; n++)
      b[n] = *(const short8*)&Bs[(wc*64 + n*16 + lr)*32 + lq*8];
    #pragma unroll
    for (int m = 0; m < 4; m++){
      #pragma unroll
      for (int n = 0; n < 4; n++){
        acc[m][n] = __builtin_amdgcn_mfma_f32_16x16x32_bf16(a[m], b[n], acc[m][n], 0, 0, 0);
      }
    }
    __syncthreads();
  }
  float* Cp = Cpart + (size_t)kz*B_*H1STR;
  #pragma unroll
  for (int m = 0; m < 4; m++){
    int grow = bx*128 + wr*64 + m*16 + lq*4;
    #pragma unroll
    for (int n = 0; n < 4; n++){
      int gcol = by*128 + wc*64 + n*16 + lr;
      #pragma unroll
      for (int r = 0; r < 4; r++)
        Cp[(size_t)(grow + r)*H1STR + gcol] = acc[m][n][r];
    }
  }
}

// ---------------- split-K reduce + bias + relu ----------------
__global__ void k_red(const float* __restrict__ Cp, const float* __restrict__ bias,
                      float* __restrict__ h1){
  size_t idx = (size_t)(blockIdx.x*256 + threadIdx.x)*4;
  if (idx >= (size_t)B_*H1STR) return;
  int col = (int)(idx % H1STR);
  float4 a = *(const float4*)(Cp + idx);
  float4 b = *(const float4*)(Cp + (size_t)B_*H1STR + idx);
  float4 c = *(const float4*)(Cp + (size_t)2*B_*H1STR + idx);
  float4 d = *(const float4*)(Cp + (size_t)3*B_*H1STR + idx);
  float4 o;
  o.x = fmaxf(a.x+b.x+c.x+d.x + ((col+0)<HID1 ? bias[col+0] : 0.f), 0.f);
  o.y = fmaxf(a.y+b.y+c.y+d.y + ((col+1)<HID1 ? bias[col+1] : 0.f), 0.f);
  o.z = fmaxf(a.z+b.z+c.z+d.z + ((col+2)<HID1 ? bias[col+2] : 0.f), 0.f);
  o.w = fmaxf(a.w+b.w+c.w+d.w + ((col+3)<HID1 ? bias[col+3] : 0.f), 0.f);
  *(float4*)(h1 + idx) = o;
}

// ---------------- fallback GEMM (round-1, known-correct) ----------------
__global__ __launch_bounds__(256) void k_gemm1(const float* __restrict__ Abuf,
                                               const float* __restrict__ W,
                                               const float* __restrict__ bias,
                                               float* __restrict__ h1){
  __shared__ unsigned short As[64][40];
  __shared__ unsigned short Bs[64][40];
  int t = threadIdx.x;
  int bx = blockIdx.x, by = blockIdx.y;
  int r0 = t >> 3;
  int kc = (t & 7) * 4;
  int wv = t >> 6, lane = t & 63, lr = lane & 15, lq = lane >> 4;
  f32x4 acc[4] = {};
  for (int ks = 0; ks < KSTEPS; ks++){
    int gk = ks*32 + kc;
    bool kval = (gk < FLATK);
    #pragma unroll
    for (int rr = 0; rr < 2; rr++){
      int r = r0 + rr*32;
      float4 va = make_float4(0.f,0.f,0.f,0.f);
      if (kval) va = *(const float4*)&Abuf[(size_t)(bx*64 + r)*FLATK + gk];
      ushort4 ua; ua.x = f2bf(va.x); ua.y = f2bf(va.y); ua.z = f2bf(va.z); ua.w = f2bf(va.w);
      *(ushort4*)&As[r][kc] = ua;
      int gn = by*64 + r;
      float4 vb = make_float4(0.f,0.f,0.f,0.f);
      if (kval && gn < HID1) vb = *(const float4*)&W[(size_t)gn*FLATK + gk];
      ushort4 ub; ub.x = f2bf(vb.x); ub.y = f2bf(vb.y); ub.z = f2bf(vb.z); ub.w = f2bf(vb.w);
      *(ushort4*)&Bs[r][kc] = ub;
    }
    __syncthreads();
    short8 a = *(const short8*)&As[wv*16 + lr][lq*8];
    #pragma unroll
    for (int j = 0; j < 4; j++){
      short8 b = *(const short8*)&Bs[j*16 + lr][lq*8];
      acc[j] = __builtin_amdgcn_mfma_f32_16x16x32_bf16(a, b, acc[j], 0, 0, 0);
    }
    __syncthreads();
  }
  #pragma unroll
  for (int j = 0; j < 4; j++){
    #pragma unroll
    for (int r = 0; r < 4; r++){
      int m = wv*16 + lq*4 + r;
      int n = j*16 + lr;
      int gn = by*64 + n;
      if (gn < HID1){
        int gb = bx*64 + m;
        float v = acc[j][r] + bias[gn];
        h1[(size_t)gb*H1STR + gn] = fmaxf(v, 0.0f);
      }
    }
  }
}

// ---------------- out1 layer 2 ----------------
__global__ __launch_bounds__(256) void k_gemm2(const float* __restrict__ h1,
                                               const float* __restrict__ w2,
                                               const float* __restrict__ b2,
                                               float* __restrict__ o1){
  __shared__ float hs[16][68];
  __shared__ float wsm[16][68];
  int t = threadIdx.x;
  int bx = blockIdx.x, by = blockIdx.y;
  int r = t >> 4, c4 = (t & 15) * 4;
  int bi = t >> 4, oi = t & 15;
  float acc = 0.f;
  for (int ks = 0; ks < 44; ks++){
    int gk = ks*64 + c4;
    float4 va = make_float4(0.f,0.f,0.f,0.f);
    if (gk < HID1) va = *(const float4*)&h1[(size_t)(bx*16 + r)*H1STR + gk];
    *(float4*)&hs[r][c4] = va;
    int go = by*16 + r;
    float4 vb = make_float4(0.f,0.f,0.f,0.f);
    if (gk < HID1 && go < NOUT) vb = *(const float4*)&w2[(size_t)go*HID1 + gk];
    *(float4*)&wsm[r][c4] = vb;
    __syncthreads();
    #pragma unroll 8
    for (int k = 0; k < 64; k++) acc += hs[bi][k] * wsm[oi][k];
    __syncthreads();
  }
  int go = by*16 + oi;
  if (go < NOUT) o1[(size_t)(bx*16 + bi)*NOUT + go] = acc + b2[go];
}

// ---------------- final reg2 MLP ----------------
__global__ void k_reg2(const float* __restrict__ o1, const float* __restrict__ xin,
                       const float* __restrict__ w1, const float* __restrict__ b1,
                       const float* __restrict__ w2, const float* __restrict__ b2,
                       float* __restrict__ outp){
  __shared__ float s[360];
  __shared__ float tt[180];
  int b = blockIdx.x, t = threadIdx.x;
  if (t < 180){
    s[2*t]   = o1[b*NOUT + t];
    s[2*t+1] = (xin[(size_t)b*SX*XROW + t*XROW + (XROW-1)] - 400.0f) * 0.01f;
  }
  __syncthreads();
  if (t < 180){
    float a = b1[t];
    for (int j = 0; j < 360; j++) a += s[j] * w1[t*360 + j];
    tt[t] = fmaxf(a, 0.0f);
  }
  __syncthreads();
  if (t < 180){
    float a = b2[t];
    for (int j = 0; j < 180; j++) a += tt[j] * w2[t*180 + j];
    outp[b*NOUT + t] = a*100.0f + 400.0f;
  }
}

extern "C" void kernel_launch(void* const* d_in, const int* in_sizes, int n_in,
                              void* d_out, int out_size, void* d_ws, size_t ws_size,
                              hipStream_t stream){
  const float* xin   = (const float*)d_in[0];
  const float* wA[2] = {(const float*)d_in[1], (const float*)d_in[3]};
  const float* wB[2] = {(const float*)d_in[2], (const float*)d_in[4]};
  const float* o1w1  = (const float*)d_in[5];
  const float* o1b1  = (const float*)d_in[6];
  const float* o1w2  = (const float*)d_in[7];
  const float* o1b2  = (const float*)d_in[8];
  const float* r2w1  = (const float*)d_in[9];
  const float* r2b1  = (const float*)d_in[10];
  const float* r2w2  = (const float*)d_in[11];
  const float* r2b2  = (const float*)d_in[12];
  float* ws  = (float*)d_ws;
  float* out = (float*)d_out;

  // layout (float slots)
  size_t oA   = 0;                                    // 71,884,800
  size_t oYre = oA   + (size_t)B_*NC*IMG;
  size_t oYim = oYre + (size_t)B_*NC*SX*16;
  size_t oZre = oYim + (size_t)B_*NC*SX*16;
  size_t oZim = oZre + (size_t)B_*NC*512;
  size_t oZ2r = oZim + (size_t)B_*NC*512;
  size_t oZ2i = oZ2r + (size_t)B_*NC*512;
  size_t oSt  = oZ2i + (size_t)B_*NC*512;             // unused slot kept for layout stability
  size_t oH1  = oSt  + (size_t)B_*NC*2;
  size_t oO1  = oH1  + (size_t)B_*H1STR;
  size_t oCFy = oO1  + (size_t)B_*NOUT;
  size_t oSFy = oCFy + 16*SY;
  size_t oCFx = oSFy + 16*SY;
  size_t oSFx = oCFx + 32*SX;
  size_t oCp  = oSFx + 32*SX;                         // 98,960,704
  size_t oAbf = oCp  + (size_t)4*B_*H1STR;            // 110,495,040
  size_t oWbf = oAbf + (size_t)B_*KPAD/2;             // 146,441,536
  size_t oEnd = oWbf + (size_t)HID1*KPAD/2;           // 245,013,568

  float *A = ws + oA, *Yre = ws + oYre, *Yim = ws + oYim;
  float *Zre = ws + oZre, *Zim = ws + oZim, *Z2r = ws + oZ2r, *Z2i = ws + oZ2i;
  float *H1 = ws + oH1, *O1 = ws + oO1;
  float *cFy = ws + oCFy, *sFy = ws + oSFy, *cFx = ws + oCFx, *sFx = ws + oSFx;
  float *Cpart = ws + oCp;
  unsigned short *Abf = (unsigned short*)(ws + oAbf);
  unsigned short *Wbf = (unsigned short*)(ws + oWbf);

  const bool fast = (ws_size >= oEnd*4);

  k_tables<<<23, 256, 0, stream>>>(cFy, sFy, cFx, sFx);
  k_build<<<dim3(92, B_), 256, 0, stream>>>(xin, A);

  for (int L = 0; L < 2; L++){
    k_statnorm<0,0><<<B_*NC, 256, 0, stream>>>(A, nullptr);
    k_fwd_y<<<B_*NC*SX/4, 256, 0, stream>>>(A, cFy, sFy, Yre, Yim);
    k_fwd_x<<<B_*NC, 256, 0, stream>>>(Yre, Yim, cFx, sFx, Zre, Zim);
    k_mix<<<(B_*NC*512)/256, 256, 0, stream>>>(Zre, Zim, wA[L], wB[L], Z2r, Z2i);
    k_inv_x<<<B_*NC, 256, 0, stream>>>(Z2r, Z2i, cFx, sFx, Yre, Yim);
    k_inv_y<<<dim3(92, B_*NC), 256, 0, stream>>>(Yre, Yim, cFy, sFy, A);
    if (L == 0 || !fast){
      k_statnorm<1,0><<<B_*NC, 256, 0, stream>>>(A, nullptr);
    } else {
      k_statnorm<1,1><<<B_*NC, 256, 0, stream>>>(A, Abf);
    }
  }

  if (fast){
    k_padA<<<8, 256, 0, stream>>>(Abf);
    k_cvt_w<<<dim3((KPAD/8 + 255)/256, HID1), 256, 0, stream>>>(o1w1, Wbf);
    k_gemm_fast<<<dim3(8, 22, 4), 256, 0, stream>>>(Abf, Wbf, Cpart);
    k_red<<<(B_*H1STR/4 + 255)/256, 256, 0, stream>>>(Cpart, o1b1, H1);
  } else {
    k_gemm1<<<dim3(16, 44), 256, 0, stream>>>(A, o1w1, o1b1, H1);
  }

  k_gemm2<<<dim3(64, 12), 256, 0, stream>>>(H1, o1w2, o1b2, O1);
  k_reg2<<<B_, 192, 0, stream>>>(O1, xin, r2w1, r2b1, r2w2, r2b2, out);
}

// Round 3
// 3201.408 us; speedup vs baseline: 3.8176x; 2.1859x over previous
//
#include <hip/hip_runtime.h>
#include <hip/hip_bf16.h>
#include <math.h>

#ifndef M_PI
#define M_PI 3.14159265358979323846
#endif

#define B_    1024
#define SX    180
#define SY    130
#define NC    3
#define IMG   23400
#define FLATK 70200
#define KPAD  70208
#define HID1  2808
#define NOUT  180
#define XROW  131
#define H1STR 2816
#define KSTEPS 2194   // KPAD/32
#define KCH    549    // ceil(KSTEPS/4)

typedef __attribute__((ext_vector_type(8))) short short8;
typedef __attribute__((ext_vector_type(4))) float f32x4;
typedef __attribute__((address_space(3))) unsigned int lds_u32;
typedef __attribute__((address_space(1))) const unsigned int glb_u32;

__device__ __forceinline__ unsigned short f2bf(float f){
  __hip_bfloat16 h = __float2bfloat16(f);
  return __builtin_bit_cast(unsigned short, h);
}
__device__ __forceinline__ float bf2f(unsigned short u){
  __hip_bfloat16 h = __builtin_bit_cast(__hip_bfloat16, u);
  return __bfloat162float(h);
}
__device__ __forceinline__ void split_bf(float f, unsigned short &hi, unsigned short &lo){
  hi = f2bf(f);
  lo = f2bf(f - bf2f(hi));
}
__device__ __forceinline__ void gl_lds16(const void* g, void* l){
  __builtin_amdgcn_global_load_lds((glb_u32*)g, (lds_u32*)l, 16, 0, 0);
}

// ---------------- tables ----------------
// cFy/sFy: [16][130] for inv_y.  cFx/sFx: [32][180] for inv_x.
// Ty: [32][160] fwd-y GEMM table: row 2ky -> cos, 2ky+1 -> -sin; zeros y>=130.
// Tx: [64][192] fwd-x GEMM table: row 2kxi -> cos, 2kxi+1 -> +sin; zeros x>=180.
__global__ void k_tables(float* __restrict__ cFy, float* __restrict__ sFy,
                         float* __restrict__ cFx, float* __restrict__ sFx,
                         float* __restrict__ Ty,  float* __restrict__ Tx){
  int i = blockIdx.x*256 + threadIdx.x;
  if (i < 16*SY){
    int ky = i / SY, y = i % SY;
    double ang = 2.0*M_PI*(double)((ky*y) % SY)/(double)SY;
    cFy[i] = (float)cos(ang); sFy[i] = (float)sin(ang);
  }
  if (i < 32*SX){
    int kxi = i / SX, x = i % SX;
    int kx = (kxi < 16) ? kxi : (kxi + 148);
    double ang = 2.0*M_PI*(double)((kx*x) % SX)/(double)SX;
    cFx[i] = (float)cos(ang); sFx[i] = (float)sin(ang);
  }
  if (i < 32*160){
    int m = i / 160, y = i % 160;
    int ky = m >> 1, ri = m & 1;
    float v = 0.f;
    if (y < SY){
      double ang = 2.0*M_PI*(double)((ky*y) % SY)/(double)SY;
      v = ri ? (float)(-sin(ang)) : (float)cos(ang);
    }
    Ty[i] = v;
  }
  if (i < 64*192){
    int n = i / 192, x = i % 192;
    int kxi = n >> 1, ri = n & 1;
    float v = 0.f;
    if (x < SX){
      int kx = (kxi < 16) ? kxi : (kxi + 148);
      double ang = 2.0*M_PI*(double)((kx*x) % SX)/(double)SX;
      v = ri ? (float)sin(ang) : (float)cos(ang);
    }
    Tx[i] = v;
  }
}

// ---------------- build h = [x, gridx, gridy] ----------------
__global__ void k_build(const float* __restrict__ xin, float* __restrict__ A){
  int b = blockIdx.y;
  int i = blockIdx.x*256 + threadIdx.x;
  if (i >= IMG) return;
  int x = i / SY, y = i - x*SY;
  float v = xin[(size_t)b*SX*XROW + x*XROW + y];
  size_t base = (size_t)b*NC*IMG;
  A[base + i]         = v;
  A[base + IMG + i]   = (float)x * (1.0f/179.0f);
  A[base + 2*IMG + i] = (float)y * (1.0f/129.0f);
}

// ---------------- stats only (norm folded into fwd_y) ----------------
__global__ __launch_bounds__(256) void k_stats(const float* __restrict__ A, float* __restrict__ st){
  int bc = blockIdx.x;
  const float4* p4 = (const float4*)(A + (size_t)bc*IMG);
  float s = 0.f, ss = 0.f;
  for (int i = threadIdx.x; i < IMG/4; i += 256){
    float4 v = p4[i];
    s  += v.x+v.y+v.z+v.w;
    ss += v.x*v.x+v.y*v.y+v.z*v.z+v.w*v.w;
  }
  for (int o = 32; o >= 1; o >>= 1){ s += __shfl_down(s, o); ss += __shfl_down(ss, o); }
  __shared__ float sh[2][4];
  int wid = threadIdx.x >> 6, ln = threadIdx.x & 63;
  if (ln == 0){ sh[0][wid] = s; sh[1][wid] = ss; }
  __syncthreads();
  if (threadIdx.x == 0){
    s  = sh[0][0]+sh[0][1]+sh[0][2]+sh[0][3];
    ss = sh[1][0]+sh[1][1]+sh[1][2]+sh[1][3];
    float mean = s * (1.0f/IMG);
    float var  = ss * (1.0f/IMG) - mean*mean;
    st[bc*2]   = mean;
    st[bc*2+1] = rsqrtf(var + 1e-5f);
  }
}

// ---------------- fwd y-DFT as split-bf16 MFMA GEMM ----------------
// per (bc, xtile): C[m=0..31][n=x-local 0..63] = sum_y Ty[m][y] * A[bc][x][y]
// epilogue: normalization fixup  Y = istd*(Yraw - 130*mean*[m==0])
#define YSTR 168   // LDS k-stride (bf16): 336B rows -> 2-way banks max
__global__ __launch_bounds__(256) void k_fwd_y_mfma(const float* __restrict__ A,
                                                    const float* __restrict__ Ty,
                                                    const float* __restrict__ St,
                                                    float* __restrict__ Yt){
  __shared__ unsigned short Thi[32*YSTR], Tlo[32*YSTR];
  __shared__ unsigned short Bhi[64*YSTR], Blo[64*YSTR];
  int t = threadIdx.x;
  int xt = blockIdx.x, bc = blockIdx.y;
  // stage table: 32 rows x 160
  {
    int r = t >> 3;                    // 0..31
    #pragma unroll
    for (int j = 0; j < 5; j++){
      int c = (t & 7)*4 + j*32;        // 0..156
      float4 v = *(const float4*)&Ty[r*160 + c];
      unsigned short h0,l0,h1,l1,h2,l2,h3,l3;
      split_bf(v.x,h0,l0); split_bf(v.y,h1,l1); split_bf(v.z,h2,l2); split_bf(v.w,h3,l3);
      *(ushort4*)&Thi[r*YSTR + c] = make_ushort4(h0,h1,h2,h3);
      *(ushort4*)&Tlo[r*YSTR + c] = make_ushort4(l0,l1,l2,l3);
    }
  }
  // stage A rows: 64 x-rows x 160 (valid y 0..129)
  {
    int r = t >> 2;                    // 0..63
    int x = xt*64 + r;
    bool valid = (x < SX);
    const float* row = A + (size_t)bc*IMG + (size_t)x*SY;
    #pragma unroll
    for (int j = 0; j < 10; j++){
      int c = (t & 3)*4 + j*16;        // 0..156
      float4 v = make_float4(0.f,0.f,0.f,0.f);
      if (valid && c < 128)      v = *(const float4*)&row[c];
      else if (valid && c == 128){ v.x = row[128]; v.y = row[129]; }
      unsigned short h0,l0,h1,l1,h2,l2,h3,l3;
      split_bf(v.x,h0,l0); split_bf(v.y,h1,l1); split_bf(v.z,h2,l2); split_bf(v.w,h3,l3);
      *(ushort4*)&Bhi[r*YSTR + c] = make_ushort4(h0,h1,h2,h3);
      *(ushort4*)&Blo[r*YSTR + c] = make_ushort4(l0,l1,l2,l3);
    }
  }
  __syncthreads();
  int lane = t & 63, wv = t >> 6;
  int lr = lane & 15, lq = lane >> 4;
  int mtile = wv >> 1, nbase = wv & 1;
  f32x4 acc[2] = {};
  #pragma unroll
  for (int ks = 0; ks < 5; ks++){
    short8 ahi = *(const short8*)&Thi[(mtile*16 + lr)*YSTR + ks*32 + lq*8];
    short8 alo = *(const short8*)&Tlo[(mtile*16 + lr)*YSTR + ks*32 + lq*8];
    #pragma unroll
    for (int p = 0; p < 2; p++){
      int nrow = ((nbase + 2*p)*16 + lr)*YSTR + ks*32 + lq*8;
      short8 bhi = *(const short8*)&Bhi[nrow];
      short8 blo = *(const short8*)&Blo[nrow];
      acc[p] = __builtin_amdgcn_mfma_f32_16x16x32_bf16(ahi, bhi, acc[p], 0, 0, 0);
      acc[p] = __builtin_amdgcn_mfma_f32_16x16x32_bf16(ahi, blo, acc[p], 0, 0, 0);
      acc[p] = __builtin_amdgcn_mfma_f32_16x16x32_bf16(alo, bhi, acc[p], 0, 0, 0);
    }
  }
  float mean = St[bc*2], istd = St[bc*2+1];
  #pragma unroll
  for (int p = 0; p < 2; p++){
    int gx = xt*64 + (nbase + 2*p)*16 + lr;
    if (gx < SX){
      #pragma unroll
      for (int r = 0; r < 4; r++){
        int gm = mtile*16 + lq*4 + r;
        float v = acc[p][r];
        if (gm == 0) v -= mean * 130.0f;
        v *= istd;
        Yt[(size_t)bc*32*SX + (size_t)gm*SX + gx] = v;
      }
    }
  }
}

// ---------------- fwd x-DFT as split-bf16 MFMA GEMM ----------------
// per (bc, nh): U[m=2ky+ri][n = nh*32 + 2kxi+ri'] = sum_x Yt[m][x] * Tx[n][x]
#define XSTR 200   // LDS k-stride (bf16) for K=192
__global__ __launch_bounds__(256) void k_fwd_x_mfma(const float* __restrict__ Yt,
                                                    const float* __restrict__ Tx,
                                                    float* __restrict__ U){
  __shared__ unsigned short Thi[32*XSTR], Tlo[32*XSTR];
  __shared__ unsigned short Yhi[32*XSTR], Ylo[32*XSTR];
  int t = threadIdx.x;
  int nh = blockIdx.x, bc = blockIdx.y;
  int r = t >> 3;                      // 0..31
  #pragma unroll
  for (int j = 0; j < 6; j++){
    int c = (t & 7)*4 + j*32;          // 0..188
    // table rows nh*32 + r  (global padded to 192)
    {
      float4 v = *(const float4*)&Tx[(nh*32 + r)*192 + c];
      unsigned short h0,l0,h1,l1,h2,l2,h3,l3;
      split_bf(v.x,h0,l0); split_bf(v.y,h1,l1); split_bf(v.z,h2,l2); split_bf(v.w,h3,l3);
      *(ushort4*)&Thi[r*XSTR + c] = make_ushort4(h0,h1,h2,h3);
      *(ushort4*)&Tlo[r*XSTR + c] = make_ushort4(l0,l1,l2,l3);
    }
    {
      float4 v = make_float4(0.f,0.f,0.f,0.f);
      if (c < SX) v = *(const float4*)&Yt[(size_t)bc*32*SX + (size_t)r*SX + c];
      unsigned short h0,l0,h1,l1,h2,l2,h3,l3;
      split_bf(v.x,h0,l0); split_bf(v.y,h1,l1); split_bf(v.z,h2,l2); split_bf(v.w,h3,l3);
      *(ushort4*)&Yhi[r*XSTR + c] = make_ushort4(h0,h1,h2,h3);
      *(ushort4*)&Ylo[r*XSTR + c] = make_ushort4(l0,l1,l2,l3);
    }
  }
  __syncthreads();
  int lane = t & 63, wv = t >> 6;
  int lr = lane & 15, lq = lane >> 4;
  int mtile = wv >> 1, ntile = wv & 1;
  f32x4 acc = {};
  #pragma unroll
  for (int ks = 0; ks < 6; ks++){
    int arow = (mtile*16 + lr)*XSTR + ks*32 + lq*8;
    int brow = (ntile*16 + lr)*XSTR + ks*32 + lq*8;
    short8 ahi = *(const short8*)&Yhi[arow];
    short8 alo = *(const short8*)&Ylo[arow];
    short8 bhi = *(const short8*)&Thi[brow];
    short8 blo = *(const short8*)&Tlo[brow];
    acc = __builtin_amdgcn_mfma_f32_16x16x32_bf16(ahi, bhi, acc, 0, 0, 0);
    acc = __builtin_amdgcn_mfma_f32_16x16x32_bf16(ahi, blo, acc, 0, 0, 0);
    acc = __builtin_amdgcn_mfma_f32_16x16x32_bf16(alo, bhi, acc, 0, 0, 0);
  }
  int gn = nh*32 + ntile*16 + lr;
  #pragma unroll
  for (int rr = 0; rr < 4; rr++){
    int gm = mtile*16 + lq*4 + rr;
    U[(size_t)bc*2048 + (size_t)gm*64 + gn] = acc[rr];
  }
}

// ---------------- channel mix (reads U, writes Z2) ----------------
__global__ void k_mix(const float* __restrict__ U,
                      const float* __restrict__ w1, const float* __restrict__ w2,
                      float* __restrict__ Z2r, float* __restrict__ Z2i){
  int idx = blockIdx.x*256 + threadIdx.x;
  if (idx >= B_*NC*512) return;
  int ky = idx & 15;
  int kxi = (idx >> 4) & 31;
  int bo = idx >> 9;
  int o = bo % 3, b = bo / 3;
  const float* w = (kxi < 16) ? w1 : w2;
  int kxm = kxi & 15;
  float ar = 0.f, ai = 0.f;
  #pragma unroll
  for (int i = 0; i < 3; i++){
    size_t base = ((size_t)(b*3 + i)*32);
    float P = U[(base + 2*ky  )*64 + 2*kxi  ];
    float Q = U[(base + 2*ky  )*64 + 2*kxi+1];
    float R = U[(base + 2*ky+1)*64 + 2*kxi  ];
    float S = U[(base + 2*ky+1)*64 + 2*kxi+1];
    float zr = P + S;
    float zi = R - Q;
    size_t wo = ((((size_t)i*3 + o)*16 + kxm)*16 + ky)*2;
    float wr = w[wo], wi = w[wo+1];
    ar += zr*wr - zi*wi;
    ai += zr*wi + zi*wr;
  }
  Z2r[idx] = ar; Z2i[idx] = ai;
}

// ---------------- inverse x-DFT ----------------
__global__ __launch_bounds__(256) void k_inv_x(const float* __restrict__ Z2r, const float* __restrict__ Z2i,
                                               const float* __restrict__ cFx, const float* __restrict__ sFx,
                                               float* __restrict__ Gre, float* __restrict__ Gim){
  int bo = blockIdx.x;
  __shared__ float Zr[512], Zi[512];
  for (int i = threadIdx.x; i < 512; i += 256){
    Zr[i] = Z2r[(size_t)bo*512 + i];
    Zi[i] = Z2i[(size_t)bo*512 + i];
  }
  __syncthreads();
  for (int o = threadIdx.x; o < SX*16; o += 256){
    int ky = o & 15, x = o >> 4;
    float gr = 0.f, gi = 0.f;
    #pragma unroll
    for (int k = 0; k < 32; k++){
      float zr = Zr[k*16+ky], zi = Zi[k*16+ky];
      float c = cFx[k*SX+x], s = sFx[k*SX+x];
      gr += zr*c - zi*s;
      gi += zr*s + zi*c;
    }
    size_t oo = (size_t)bo*SX*16 + o;
    Gre[oo] = gr * (1.0f/SX);
    Gim[oo] = gi * (1.0f/SX);
  }
}

// ---------------- inverse y (c2r; ky=0 imaginary ignored) ----------------
__global__ void k_inv_y(const float* __restrict__ Gre, const float* __restrict__ Gim,
                        const float* __restrict__ cFy, const float* __restrict__ sFy,
                        float* __restrict__ A){
  int bo = blockIdx.y;
  int i = blockIdx.x*256 + threadIdx.x;
  if (i >= IMG) return;
  int x = i / SY, y = i - x*SY;
  const float* gr = Gre + ((size_t)bo*SX + x)*16;
  const float* gi = Gim + ((size_t)bo*SX + x)*16;
  float acc = gr[0];
  #pragma unroll
  for (int ky = 1; ky < 16; ky++){
    acc += 2.0f * (gr[ky]*cFy[ky*SY + y] - gi[ky]*sFy[ky*SY + y]);
  }
  A[(size_t)bo*IMG + i] = acc * (1.0f/SY);
}

// ---------------- fused instance-norm + gelu (+optional bf16 out) ----------------
template<int GELU, int OUTBF>
__global__ __launch_bounds__(256) void k_statnorm(float* __restrict__ A,
                                                  unsigned short* __restrict__ Abf){
  int bc = blockIdx.x;
  float* p = A + (size_t)bc*IMG;
  float4* p4 = (float4*)p;
  float s = 0.f, ss = 0.f;
  for (int i = threadIdx.x; i < IMG/4; i += 256){
    float4 v = p4[i];
    s  += v.x+v.y+v.z+v.w;
    ss += v.x*v.x+v.y*v.y+v.z*v.z+v.w*v.w;
  }
  for (int o = 32; o >= 1; o >>= 1){ s += __shfl_down(s, o); ss += __shfl_down(ss, o); }
  __shared__ float sh[2][4];
  __shared__ float mb[2];
  int wid = threadIdx.x >> 6, ln = threadIdx.x & 63;
  if (ln == 0){ sh[0][wid] = s; sh[1][wid] = ss; }
  __syncthreads();
  if (threadIdx.x == 0){
    s  = sh[0][0]+sh[0][1]+sh[0][2]+sh[0][3];
    ss = sh[1][0]+sh[1][1]+sh[1][2]+sh[1][3];
    float mean = s * (1.0f/IMG);
    float var  = ss * (1.0f/IMG) - mean*mean;
    mb[0] = mean; mb[1] = rsqrtf(var + 1e-5f);
  }
  __syncthreads();
  float mean = mb[0], istd = mb[1];
  int b = bc/3, c = bc - b*3;
  for (int i = threadIdx.x; i < IMG/4; i += 256){
    float4 v = p4[i];
    float r[4] = {(v.x-mean)*istd, (v.y-mean)*istd, (v.z-mean)*istd, (v.w-mean)*istd};
    if (GELU){
      #pragma unroll
      for (int j = 0; j < 4; j++)
        r[j] = 0.5f * r[j] * (1.0f + erff(r[j] * 0.70710678118654752f));
    }
    if (OUTBF){
      ushort4 u; u.x = f2bf(r[0]); u.y = f2bf(r[1]); u.z = f2bf(r[2]); u.w = f2bf(r[3]);
      *(ushort4*)&Abf[(size_t)b*KPAD + c*IMG + i*4] = u;
    } else {
      p4[i] = make_float4(r[0], r[1], r[2], r[3]);
    }
  }
}

// ---------------- W fp32 -> bf16 (padded to KPAD) ----------------
__global__ void k_cvt_w(const float* __restrict__ W, unsigned short* __restrict__ Wbf){
  int row = blockIdx.y;
  int gi = blockIdx.x*256 + threadIdx.x;
  if (gi >= KPAD/8) return;
  unsigned short* dst = Wbf + (size_t)row*KPAD + gi*8;
  if (gi*8 >= FLATK){
    *(ushort4*)dst = make_ushort4(0,0,0,0);
    *(ushort4*)(dst+4) = make_ushort4(0,0,0,0);
    return;
  }
  const float4* src = (const float4*)(W + (size_t)row*FLATK + gi*8);
  float4 v0 = src[0], v1 = src[1];
  ushort4 u0, u1;
  u0.x=f2bf(v0.x); u0.y=f2bf(v0.y); u0.z=f2bf(v0.z); u0.w=f2bf(v0.w);
  u1.x=f2bf(v1.x); u1.y=f2bf(v1.y); u1.z=f2bf(v1.z); u1.w=f2bf(v1.w);
  *(ushort4*)dst = u0;
  *(ushort4*)(dst+4) = u1;
}

// ---------------- zero-pad A bf16 k-tail ----------------
__global__ void k_padA(unsigned short* __restrict__ Abf){
  int t = blockIdx.x*256 + threadIdx.x;
  if (t >= B_*2) return;
  int b = t >> 1, h = t & 1;
  *(ushort4*)&Abf[(size_t)b*KPAD + FLATK + h*4] = make_ushort4(0,0,0,0);
}

// ---------------- big GEMM: 128x128 tile, BK=32, global_load_lds, split-K ----------------
__global__ __launch_bounds__(256) void k_gemm_fast(const unsigned short* __restrict__ Abf,
                                                   const unsigned short* __restrict__ Wbf,
                                                   float* __restrict__ Cpart){
  __shared__ unsigned short As[128*32];
  __shared__ unsigned short Bs[128*32];
  int t = threadIdx.x;
  int bx = blockIdx.x, by = blockIdx.y, kz = blockIdx.z;
  int ks0 = kz*KCH, ks1 = min(ks0 + KCH, KSTEPS);
  int lane = t & 63, wv = t >> 6;
  int lr = lane & 15, lq = lane >> 4;
  int wr = wv >> 1, wc = wv & 1;
  int srow = t >> 2, scol = (t & 3) * 8;
  const unsigned short* ga0 = Abf + (size_t)(bx*128 + srow)*KPAD + scol;
  const unsigned short* ga1 = ga0 + (size_t)64*KPAD;
  int wrow0 = min(by*128 + srow, HID1-1);
  int wrow1 = min(by*128 + 64 + srow, HID1-1);
  const unsigned short* gb0 = Wbf + (size_t)wrow0*KPAD + scol;
  const unsigned short* gb1 = Wbf + (size_t)wrow1*KPAD + scol;
  unsigned short* la0 = &As[srow*32 + scol];
  unsigned short* la1 = &As[(64+srow)*32 + scol];
  unsigned short* lb0 = &Bs[srow*32 + scol];
  unsigned short* lb1 = &Bs[(64+srow)*32 + scol];
  f32x4 acc[4][4] = {};
  for (int ks = ks0; ks < ks1; ks++){
    size_t gk = (size_t)ks*32;
    gl_lds16(ga0 + gk, la0);
    gl_lds16(ga1 + gk, la1);
    gl_lds16(gb0 + gk, lb0);
    gl_lds16(gb1 + gk, lb1);
    __syncthreads();
    short8 a[4], b[4];
    #pragma unroll
    for (int m = 0; m < 4; m++)
      a[m] = *(const short8*)&As[(wr*64 + m*16 + lr)*32 + lq*8];
    #pragma unroll
    for (int n = 0; n < 4; n++)
      b[n] = *(const short8*)&Bs[(wc*64 + n*16 + lr)*32 + lq*8];
    #pragma unroll
    for (int m = 0; m < 4; m++){
      #pragma unroll
      for (int n = 0; n < 4; n++){
        acc[m][n] = __builtin_amdgcn_mfma_f32_16x16x32_bf16(a[m], b[n], acc[m][n], 0, 0, 0);
      }
    }
    __syncthreads();
  }
  float* Cp = Cpart + (size_t)kz*B_*H1STR;
  #pragma unroll
  for (int m = 0; m < 4; m++){
    int grow = bx*128 + wr*64 + m*16 + lq*4;
    #pragma unroll
    for (int n = 0; n < 4; n++){
      int gcol = by*128 + wc*64 + n*16 + lr;
      #pragma unroll
      for (int r = 0; r < 4; r++)
        Cp[(size_t)(grow + r)*H1STR + gcol] = acc[m][n][r];
    }
  }
}

// ---------------- split-K reduce + bias + relu ----------------
__global__ void k_red(const float* __restrict__ Cp, const float* __restrict__ bias,
                      float* __restrict__ h1){
  size_t idx = (size_t)(blockIdx.x*256 + threadIdx.x)*4;
  if (idx >= (size_t)B_*H1STR) return;
  int col = (int)(idx % H1STR);
  float4 a = *(const float4*)(Cp + idx);
  float4 b = *(const float4*)(Cp + (size_t)B_*H1STR + idx);
  float4 c = *(const float4*)(Cp + (size_t)2*B_*H1STR + idx);
  float4 d = *(const float4*)(Cp + (size_t)3*B_*H1STR + idx);
  float4 o;
  o.x = fmaxf(a.x+b.x+c.x+d.x + ((col+0)<HID1 ? bias[col+0] : 0.f), 0.f);
  o.y = fmaxf(a.y+b.y+c.y+d.y + ((col+1)<HID1 ? bias[col+1] : 0.f), 0.f);
  o.z = fmaxf(a.z+b.z+c.z+d.z + ((col+2)<HID1 ? bias[col+2] : 0.f), 0.f);
  o.w = fmaxf(a.w+b.w+c.w+d.w + ((col+3)<HID1 ? bias[col+3] : 0.f), 0.f);
  *(float4*)(h1 + idx) = o;
}

// ---------------- out1 layer 2 ----------------
__global__ __launch_bounds__(256) void k_gemm2(const float* __restrict__ h1,
                                               const float* __restrict__ w2,
                                               const float* __restrict__ b2,
                                               float* __restrict__ o1){
  __shared__ float hs[16][68];
  __shared__ float wsm[16][68];
  int t = threadIdx.x;
  int bx = blockIdx.x, by = blockIdx.y;
  int r = t >> 4, c4 = (t & 15) * 4;
  int bi = t >> 4, oi = t & 15;
  float acc = 0.f;
  for (int ks = 0; ks < 44; ks++){
    int gk = ks*64 + c4;
    float4 va = make_float4(0.f,0.f,0.f,0.f);
    if (gk < HID1) va = *(const float4*)&h1[(size_t)(bx*16 + r)*H1STR + gk];
    *(float4*)&hs[r][c4] = va;
    int go = by*16 + r;
    float4 vb = make_float4(0.f,0.f,0.f,0.f);
    if (gk < HID1 && go < NOUT) vb = *(const float4*)&w2[(size_t)go*HID1 + gk];
    *(float4*)&wsm[r][c4] = vb;
    __syncthreads();
    #pragma unroll 8
    for (int k = 0; k < 64; k++) acc += hs[bi][k] * wsm[oi][k];
    __syncthreads();
  }
  int go = by*16 + oi;
  if (go < NOUT) o1[(size_t)(bx*16 + bi)*NOUT + go] = acc + b2[go];
}

// ---------------- final reg2 MLP ----------------
__global__ void k_reg2(const float* __restrict__ o1, const float* __restrict__ xin,
                       const float* __restrict__ w1, const float* __restrict__ b1,
                       const float* __restrict__ w2, const float* __restrict__ b2,
                       float* __restrict__ outp){
  __shared__ float s[360];
  __shared__ float tt[180];
  int b = blockIdx.x, t = threadIdx.x;
  if (t < 180){
    s[2*t]   = o1[b*NOUT + t];
    s[2*t+1] = (xin[(size_t)b*SX*XROW + t*XROW + (XROW-1)] - 400.0f) * 0.01f;
  }
  __syncthreads();
  if (t < 180){
    float a = b1[t];
    for (int j = 0; j < 360; j++) a += s[j] * w1[t*360 + j];
    tt[t] = fmaxf(a, 0.0f);
  }
  __syncthreads();
  if (t < 180){
    float a = b2[t];
    for (int j = 0; j < 180; j++) a += tt[j] * w2[t*180 + j];
    outp[b*NOUT + t] = a*100.0f + 400.0f;
  }
}

extern "C" void kernel_launch(void* const* d_in, const int* in_sizes, int n_in,
                              void* d_out, int out_size, void* d_ws, size_t ws_size,
                              hipStream_t stream){
  const float* xin   = (const float*)d_in[0];
  const float* wA[2] = {(const float*)d_in[1], (const float*)d_in[3]};
  const float* wB[2] = {(const float*)d_in[2], (const float*)d_in[4]};
  const float* o1w1  = (const float*)d_in[5];
  const float* o1b1  = (const float*)d_in[6];
  const float* o1w2  = (const float*)d_in[7];
  const float* o1b2  = (const float*)d_in[8];
  const float* r2w1  = (const float*)d_in[9];
  const float* r2b1  = (const float*)d_in[10];
  const float* r2w2  = (const float*)d_in[11];
  const float* r2b2  = (const float*)d_in[12];
  float* ws  = (float*)d_ws;
  float* out = (float*)d_out;

  // layout (float slots)
  size_t oA   = 0;
  size_t oYre = oA   + (size_t)B_*NC*IMG;              // Yt overlays Yre+Yim (17.69M floats)
  size_t oYim = oYre + (size_t)B_*NC*SX*16;
  size_t oZre = oYim + (size_t)B_*NC*SX*16;
  size_t oZim = oZre + (size_t)B_*NC*512;
  size_t oZ2r = oZim + (size_t)B_*NC*512;
  size_t oZ2i = oZ2r + (size_t)B_*NC*512;
  size_t oSt  = oZ2i + (size_t)B_*NC*512;
  size_t oH1  = oSt  + (size_t)B_*NC*2;
  size_t oO1  = oH1  + (size_t)B_*H1STR;
  size_t oCFy = oO1  + (size_t)B_*NOUT;
  size_t oSFy = oCFy + 16*SY;
  size_t oCFx = oSFy + 16*SY;
  size_t oSFx = oCFx + 32*SX;
  size_t oTy  = oSFx + 32*SX;
  size_t oTx  = oTy  + 32*160;
  size_t oCp  = oTx  + 64*192;                          // U (6.29M) overlays Cpart head
  size_t oAbf = oCp  + (size_t)4*B_*H1STR;
  size_t oWbf = oAbf + (size_t)B_*KPAD/2;
  size_t oEnd = oWbf + (size_t)HID1*KPAD/2;

  float *A = ws + oA;
  float *Yt = ws + oYre;                                // fwd-path layout [bc][32][180]
  float *Gre = ws + oYre, *Gim = ws + oYim;             // inv-path layout (after fwd done)
  float *Z2r = ws + oZ2r, *Z2i = ws + oZ2i;
  float *St = ws + oSt, *H1 = ws + oH1, *O1 = ws + oO1;
  float *cFy = ws + oCFy, *sFy = ws + oSFy, *cFx = ws + oCFx, *sFx = ws + oSFx;
  float *Ty = ws + oTy, *Tx = ws + oTx;
  float *Cpart = ws + oCp;
  float *U = ws + oCp;                                  // reused before gemm
  unsigned short *Abf = (unsigned short*)(ws + oAbf);
  unsigned short *Wbf = (unsigned short*)(ws + oWbf);

  const bool fast = (ws_size >= oEnd*4);

  k_tables<<<48, 256, 0, stream>>>(cFy, sFy, cFx, sFx, Ty, Tx);
  k_build<<<dim3(92, B_), 256, 0, stream>>>(xin, A);

  for (int L = 0; L < 2; L++){
    k_stats<<<B_*NC, 256, 0, stream>>>(A, St);
    k_fwd_y_mfma<<<dim3(3, B_*NC), 256, 0, stream>>>(A, Ty, St, Yt);
    k_fwd_x_mfma<<<dim3(2, B_*NC), 256, 0, stream>>>(Yt, Tx, U);
    k_mix<<<(B_*NC*512)/256, 256, 0, stream>>>(U, wA[L], wB[L], Z2r, Z2i);
    k_inv_x<<<B_*NC, 256, 0, stream>>>(Z2r, Z2i, cFx, sFx, Gre, Gim);
    k_inv_y<<<dim3(92, B_*NC), 256, 0, stream>>>(Gre, Gim, cFy, sFy, A);
    if (L == 0 || !fast){
      k_statnorm<1,0><<<B_*NC, 256, 0, stream>>>(A, nullptr);
    } else {
      k_statnorm<1,1><<<B_*NC, 256, 0, stream>>>(A, Abf);
    }
  }

  if (fast){
    k_padA<<<8, 256, 0, stream>>>(Abf);
    k_cvt_w<<<dim3((KPAD/8 + 255)/256, HID1), 256, 0, stream>>>(o1w1, Wbf);
    k_gemm_fast<<<dim3(8, 22, 4), 256, 0, stream>>>(Abf, Wbf, Cpart);
    k_red<<<(B_*H1STR/4 + 255)/256, 256, 0, stream>>>(Cpart, o1b1, H1);
  } else {
    // (ws proved large enough in round 2; this branch kept only as safety)
    k_gemm2<<<dim3(64, 12), 256, 0, stream>>>(H1, o1w2, o1b2, O1);
  }

  k_gemm2<<<dim3(64, 12), 256, 0, stream>>>(H1, o1w2, o1b2, O1);
  k_reg2<<<B_, 192, 0, stream>>>(O1, xin, r2w1, r2b1, r2w2, r2b2, out);
}

// Round 5
// 1797.304 us; speedup vs baseline: 6.7999x; 1.7812x over previous
//
#include <hip/hip_runtime.h>
#include <hip/hip_bf16.h>
#include <math.h>

#ifndef M_PI
#define M_PI 3.14159265358979323846
#endif

#define B_    1024
#define SX    180
#define SY    130
#define NC    3
#define IMG   23400
#define FLATK 70200
#define KPAD  70208
#define HID1  2808
#define NOUT  180
#define XROW  131
#define H1STR 2816
#define KSTEPS 2194   // KPAD/32
#define KCH    549    // ceil(KSTEPS/4)

typedef __attribute__((ext_vector_type(8))) short short8;
typedef __attribute__((ext_vector_type(4))) float f32x4;
typedef __attribute__((address_space(3))) unsigned int lds_u32;
typedef __attribute__((address_space(1))) const unsigned int glb_u32;

// padded table sizes (shorts) — ALL staging loop trip counts must be %64==0
#define TY_SH   5632   // 32*168=5376 -> pad 5632  (704 iters)
#define TX_SH   12800  // 64*200           (1600 iters, already %64==0)
#define TXI_SH  13824  // 192*72           (1728 iters, %64==0)
#define TIY_SH  6144   // 144*40=5760 -> pad 6144 (768 iters)

__device__ __forceinline__ unsigned short f2bf(float f){
  __hip_bfloat16 h = __float2bfloat16(f);
  return __builtin_bit_cast(unsigned short, h);
}
__device__ __forceinline__ float bf2f(unsigned short u){
  __hip_bfloat16 h = __builtin_bit_cast(__hip_bfloat16, u);
  return __bfloat162float(h);
}
__device__ __forceinline__ void split_bf(float f, unsigned short &hi, unsigned short &lo){
  hi = f2bf(f);
  lo = f2bf(f - bf2f(hi));
}
__device__ __forceinline__ void gl_lds16(const void* g, void* l){
  __builtin_amdgcn_global_load_lds((glb_u32*)g, (lds_u32*)l, 16, 0, 0);
}
__device__ __forceinline__ float gelu_f(float v){
  return 0.5f * v * (1.0f + erff(v * 0.70710678118654752f));
}

// ================= tables (split hi/lo bf16, LDS-matching strides, padded) =================
__global__ void k_tables2(unsigned short* __restrict__ TyH, unsigned short* __restrict__ TyL,
                          unsigned short* __restrict__ TxH, unsigned short* __restrict__ TxL,
                          unsigned short* __restrict__ TxiH, unsigned short* __restrict__ TxiL,
                          unsigned short* __restrict__ TiyH, unsigned short* __restrict__ TiyL){
  int i = blockIdx.x*256 + threadIdx.x;
  unsigned short h, l;
  if (i < TY_SH){
    int m = i/168, y = i%168;
    float v = 0.f;
    if (m < 32 && y < SY){
      int ky = m>>1, ri = m&1;
      double ang = 2.0*M_PI*(double)((ky*y)%SY)/(double)SY;
      v = ri ? (float)(-sin(ang)) : (float)cos(ang);
    }
    split_bf(v,h,l); TyH[i]=h; TyL[i]=l;
  }
  if (i < TX_SH){
    int n = i/200, x = i%200;
    float v = 0.f;
    if (x < SX){
      int kxi = n>>1, ri = n&1;
      int kx = (kxi<16)? kxi : kxi+148;
      double ang = 2.0*M_PI*(double)((kx*x)%SX)/(double)SX;
      v = ri ? (float)sin(ang) : (float)cos(ang);
    }
    split_bf(v,h,l); TxH[i]=h; TxL[i]=l;
  }
  if (i < TXI_SH){
    int x = i/72, k = i%72;
    float v = 0.f;
    if (x < SX && k < 64){
      int kxi = k>>1, ri = k&1;
      int kx = (kxi<16)? kxi : kxi+148;
      double ang = 2.0*M_PI*(double)((kx*x)%SX)/(double)SX;
      v = (float)((ri ? sin(ang) : cos(ang)) / (double)SX);
    }
    split_bf(v,h,l); TxiH[i]=h; TxiL[i]=l;
  }
  if (i < TIY_SH){
    int y = i/40, m = i%40;
    float v = 0.f;
    if (y < SY && m < 32){
      int ky = m>>1, ri = m&1;
      if (m == 0) v = 1.0f/(float)SY;
      else if (m == 1) v = 0.f;
      else {
        double ang = 2.0*M_PI*(double)((ky*y)%SY)/(double)SY;
        v = (float)((ri ? -2.0*sin(ang) : 2.0*cos(ang)) / (double)SY);
      }
    }
    split_bf(v,h,l); TiyH[i]=h; TiyL[i]=l;
  }
}

// ================= fused fwd: stats + fwd_y MFMA + fwd_x MFMA =================
// SRC 0: layer1, input xin fp32 (bid<B_: data ch of batch bid; bid==B_: gridx; B_+1: gridy)
// SRC 1: layer2, input A1 bf16, block = bc
template<int SRC>
__global__ __launch_bounds__(256) void k_fwd(const float* __restrict__ xin,
                                             const unsigned short* __restrict__ A1,
                                             const unsigned short* __restrict__ TyH,
                                             const unsigned short* __restrict__ TyL,
                                             const unsigned short* __restrict__ TxH,
                                             const unsigned short* __restrict__ TxL,
                                             float* __restrict__ Uout,
                                             float* __restrict__ Ug){
  constexpr int DHI = 0;
  constexpr int DLO = (SRC==0) ? 32256 : 0;                 // SRC1: unused
  constexpr int TYHo = (SRC==0) ? 64512 : 32256;
  constexpr int TYLo = TYHo + TY_SH;
  constexpr int LDSN = TYLo + TY_SH;                        // SRC0: 75776, SRC1: 43520
  constexpr int YTH = 0, YTL = 6400, TXHo = 12800, TXLo = 25600;  // phase-2 regions (<=38400)
  __shared__ unsigned short LB[LDSN];
  __shared__ float sred[2][4];
  __shared__ float mb[2];
  int t = threadIdx.x, lane = t&63, wv = t>>6, lr = lane&15, lq = lane>>4;
  int bid = blockIdx.x;

  // ---- stage Ty tables (async, full-wave trip counts) ----
  for (int i=t; i<TY_SH/8; i+=256) gl_lds16(TyH + i*8, &LB[TYHo + i*8]);
  for (int i=t; i<TY_SH/8; i+=256) gl_lds16(TyL + i*8, &LB[TYLo + i*8]);

  // ---- stage data rows [192][K=160, stride 168] + stats ----
  float s = 0.f, ss = 0.f;
  for (int i=t; i<7680; i+=256){
    int row = i/40, c4 = (i - row*40)*4;
    if (SRC == 0){
      float v[4];
      #pragma unroll
      for (int j=0;j<4;j++){
        int y = c4 + j;
        float val = 0.f;
        if (row < SX && y < SY){
          if (bid < B_)       val = xin[(size_t)bid*(SX*XROW) + row*XROW + y];
          else if (bid == B_) val = (float)row * (1.0f/179.0f);
          else                val = (float)y * (1.0f/129.0f);
        }
        s += val; ss += val*val;
        v[j] = val;
      }
      unsigned short h0,l0,h1,l1,h2,l2,h3,l3;
      split_bf(v[0],h0,l0); split_bf(v[1],h1,l1); split_bf(v[2],h2,l2); split_bf(v[3],h3,l3);
      *(ushort4*)&LB[DHI + row*168 + c4] = make_ushort4(h0,h1,h2,h3);
      *(ushort4*)&LB[DLO + row*168 + c4] = make_ushort4(l0,l1,l2,l3);
    } else {
      ushort4 d = make_ushort4(0,0,0,0);
      if (row < SX){
        const unsigned short* src = A1 + (size_t)bid*IMG + row*SY + c4;
        if (c4 <= 124){
          ushort2 a = *(const ushort2*)src;
          ushort2 b = *(const ushort2*)(src+2);
          d.x=a.x; d.y=a.y; d.z=b.x; d.w=b.y;
        } else if (c4 == 128){
          ushort2 a = *(const ushort2*)src;
          d.x=a.x; d.y=a.y;
        }
      }
      float v0=bf2f(d.x), v1=bf2f(d.y), v2=bf2f(d.z), v3=bf2f(d.w);
      s += v0+v1+v2+v3; ss += v0*v0+v1*v1+v2*v2+v3*v3;
      *(ushort4*)&LB[DHI + row*168 + c4] = d;
    }
  }
  // ---- block stats reduce ----
  for (int o = 32; o >= 1; o >>= 1){ s += __shfl_down(s,o); ss += __shfl_down(ss,o); }
  if (lane == 0){ sred[0][wv] = s; sred[1][wv] = ss; }
  __syncthreads();
  if (t == 0){
    float S = sred[0][0]+sred[0][1]+sred[0][2]+sred[0][3];
    float SS = sred[1][0]+sred[1][1]+sred[1][2]+sred[1][3];
    float mean = S * (1.0f/IMG);
    float var  = SS * (1.0f/IMG) - mean*mean;
    mb[0] = mean; mb[1] = rsqrtf(var + 1e-5f);
  }
  __syncthreads();

  // ---- phase 1: C1[m=32][x=192] = Ty x D, K=160 ----
  f32x4 acc[2][3] = {};
  #pragma unroll
  for (int ks=0; ks<5; ks++){
    short8 tyh[2], tyl[2];
    #pragma unroll
    for (int mt=0; mt<2; mt++){
      tyh[mt] = *(const short8*)&LB[TYHo + (mt*16+lr)*168 + ks*32 + lq*8];
      tyl[mt] = *(const short8*)&LB[TYLo + (mt*16+lr)*168 + ks*32 + lq*8];
    }
    #pragma unroll
    for (int j=0; j<3; j++){
      int xr = (wv*3 + j)*16 + lr;
      short8 dh = *(const short8*)&LB[DHI + xr*168 + ks*32 + lq*8];
      #pragma unroll
      for (int mt=0; mt<2; mt++){
        acc[mt][j] = __builtin_amdgcn_mfma_f32_16x16x32_bf16(tyh[mt], dh, acc[mt][j], 0,0,0);
        acc[mt][j] = __builtin_amdgcn_mfma_f32_16x16x32_bf16(tyl[mt], dh, acc[mt][j], 0,0,0);
      }
      if (SRC == 0){
        short8 dl = *(const short8*)&LB[DLO + xr*168 + ks*32 + lq*8];
        #pragma unroll
        for (int mt=0; mt<2; mt++)
          acc[mt][j] = __builtin_amdgcn_mfma_f32_16x16x32_bf16(tyh[mt], dl, acc[mt][j], 0,0,0);
      }
    }
  }
  __syncthreads();   // all phase-1 LDS reads done before overwrite

  // ---- stage Tx (async, full-wave) + write Yt split-bf16 [m][200] ----
  for (int i=t; i<TX_SH/8; i+=256) gl_lds16(TxH + i*8, &LB[TXHo + i*8]);
  for (int i=t; i<TX_SH/8; i+=256) gl_lds16(TxL + i*8, &LB[TXLo + i*8]);
  {
    float mean = mb[0], istd = mb[1];
    #pragma unroll
    for (int mt=0; mt<2; mt++){
      #pragma unroll
      for (int j=0; j<3; j++){
        int xr = (wv*3 + j)*16 + lr;
        #pragma unroll
        for (int r=0; r<4; r++){
          int m = mt*16 + lq*4 + r;
          float v = acc[mt][j][r];
          if (m == 0) v -= 130.0f*mean;
          v *= istd;
          unsigned short h,l; split_bf(v,h,l);
          LB[YTH + m*200 + xr] = h;
          LB[YTL + m*200 + xr] = l;
        }
      }
    }
  }
  __syncthreads();

  // ---- phase 2: U[m=32][n=64] = Yt x Tx, K=192 ----
  f32x4 acc2[2] = {};
  #pragma unroll
  for (int ks=0; ks<6; ks++){
    short8 txh = *(const short8*)&LB[TXHo + (wv*16+lr)*200 + ks*32 + lq*8];
    short8 txl = *(const short8*)&LB[TXLo + (wv*16+lr)*200 + ks*32 + lq*8];
    #pragma unroll
    for (int mt=0; mt<2; mt++){
      short8 yh = *(const short8*)&LB[YTH + (mt*16+lr)*200 + ks*32 + lq*8];
      short8 yl = *(const short8*)&LB[YTL + (mt*16+lr)*200 + ks*32 + lq*8];
      acc2[mt] = __builtin_amdgcn_mfma_f32_16x16x32_bf16(yh, txh, acc2[mt], 0,0,0);
      acc2[mt] = __builtin_amdgcn_mfma_f32_16x16x32_bf16(yl, txh, acc2[mt], 0,0,0);
      acc2[mt] = __builtin_amdgcn_mfma_f32_16x16x32_bf16(yh, txl, acc2[mt], 0,0,0);
    }
  }
  float* Ub;
  if (SRC == 1) Ub = Uout + (size_t)bid*2048;
  else Ub = (bid < B_) ? (Uout + (size_t)bid*2048) : (Ug + (size_t)(bid - B_)*2048);
  #pragma unroll
  for (int mt=0; mt<2; mt++){
    #pragma unroll
    for (int r=0; r<4; r++){
      int m = mt*16 + lq*4 + r;
      int n = wv*16 + lr;
      Ub[m*64 + n] = acc2[mt][r];
    }
  }
}

// ================= fused inv: mix + inv_x MFMA + inv_y MFMA + norm + gelu =================
template<int LAYER>
__global__ __launch_bounds__(256) void k_inv(const float* __restrict__ U1,
                                             const float* __restrict__ Ug,
                                             const float* __restrict__ U2,
                                             const float* __restrict__ w1,
                                             const float* __restrict__ w2,
                                             const unsigned short* __restrict__ TxiH,
                                             const unsigned short* __restrict__ TxiL,
                                             const unsigned short* __restrict__ TiyH,
                                             const unsigned short* __restrict__ TiyL,
                                             unsigned short* __restrict__ A1,
                                             unsigned short* __restrict__ Abf){
  constexpr int TXIHo = 0, TXILo = TXI_SH;                  // 0, 13824
  constexpr int TIYHo = TXILo + TXI_SH;                     // 27648
  constexpr int TIYLo = TIYHo + TIY_SH;                     // 33792
  constexpr int ZFH = TIYLo + TIY_SH;                       // 39936
  constexpr int ZFL = ZFH + 2304;                           // 42240
  constexpr int GH  = ZFL + 2304;                           // 44544
  constexpr int GL  = GH + 7680;                            // 52224 -> end 59904
  __shared__ unsigned short LB[59904];
  __shared__ float sred[2][4];
  __shared__ float mb[2];
  int t = threadIdx.x, lane = t&63, wv = t>>6, lr = lane&15, lq = lane>>4;
  int bid = blockIdx.x, b = bid/3, o = bid - b*3;

  for (int i=t; i<TXI_SH/8; i+=256) gl_lds16(TxiH + i*8, &LB[TXIHo + i*8]);
  for (int i=t; i<TXI_SH/8; i+=256) gl_lds16(TxiL + i*8, &LB[TXILo + i*8]);
  for (int i=t; i<TIY_SH/8; i+=256) gl_lds16(TiyH + i*8, &LB[TIYHo + i*8]);
  for (int i=t; i<TIY_SH/8; i+=256) gl_lds16(TiyL + i*8, &LB[TIYLo + i*8]);

  // ---- mix -> Zfold split-bf16 [32][72] ----
  #pragma unroll
  for (int pp=0; pp<2; pp++){
    int p = t + pp*256;
    int kxi = p & 31, ky = p >> 5;
    const float* w = (kxi < 16) ? w1 : w2;
    int kxm = kxi & 15;
    float ar = 0.f, ai = 0.f;
    #pragma unroll
    for (int i=0; i<3; i++){
      const float* Ui;
      if (LAYER == 0) Ui = (i==0) ? (U1 + (size_t)b*2048) : (Ug + (size_t)(i-1)*2048);
      else            Ui = U2 + ((size_t)b*3 + i)*2048;
      float P = Ui[(2*ky  )*64 + 2*kxi  ];
      float Q = Ui[(2*ky  )*64 + 2*kxi+1];
      float R = Ui[(2*ky+1)*64 + 2*kxi  ];
      float S = Ui[(2*ky+1)*64 + 2*kxi+1];
      float zr = P + S, zi = R - Q;
      size_t wo = ((((size_t)i*3 + o)*16 + kxm)*16 + ky)*2;
      float wr = w[wo], wi = w[wo+1];
      ar += zr*wr - zi*wi;
      ai += zr*wi + zi*wr;
    }
    unsigned short hr,lr_, hi,li, hn,ln;
    split_bf(ar,hr,lr_); split_bf(ai,hi,li); split_bf(-ai,hn,ln);
    LB[ZFH + (2*ky  )*72 + 2*kxi  ] = hr;  LB[ZFL + (2*ky  )*72 + 2*kxi  ] = lr_;
    LB[ZFH + (2*ky  )*72 + 2*kxi+1] = hn;  LB[ZFL + (2*ky  )*72 + 2*kxi+1] = ln;
    LB[ZFH + (2*ky+1)*72 + 2*kxi  ] = hi;  LB[ZFL + (2*ky+1)*72 + 2*kxi  ] = li;
    LB[ZFH + (2*ky+1)*72 + 2*kxi+1] = hr;  LB[ZFL + (2*ky+1)*72 + 2*kxi+1] = lr_;
  }
  __syncthreads();

  // ---- GEMM-1: C1[m=32][x=192] = Zfold x Txi, K=64 ----
  f32x4 acc1[2][3] = {};
  #pragma unroll
  for (int ks=0; ks<2; ks++){
    short8 zh[2], zl[2];
    #pragma unroll
    for (int mt=0; mt<2; mt++){
      zh[mt] = *(const short8*)&LB[ZFH + (mt*16+lr)*72 + ks*32 + lq*8];
      zl[mt] = *(const short8*)&LB[ZFL + (mt*16+lr)*72 + ks*32 + lq*8];
    }
    #pragma unroll
    for (int j=0; j<3; j++){
      int x = (wv*3 + j)*16 + lr;
      short8 txh = *(const short8*)&LB[TXIHo + x*72 + ks*32 + lq*8];
      short8 txl = *(const short8*)&LB[TXILo + x*72 + ks*32 + lq*8];
      #pragma unroll
      for (int mt=0; mt<2; mt++){
        acc1[mt][j] = __builtin_amdgcn_mfma_f32_16x16x32_bf16(zh[mt], txh, acc1[mt][j], 0,0,0);
        acc1[mt][j] = __builtin_amdgcn_mfma_f32_16x16x32_bf16(zl[mt], txh, acc1[mt][j], 0,0,0);
        acc1[mt][j] = __builtin_amdgcn_mfma_f32_16x16x32_bf16(zh[mt], txl, acc1[mt][j], 0,0,0);
      }
    }
  }
  // ---- write G^T split-bf16 [x=192][40] (disjoint region; barrier before reads) ----
  #pragma unroll
  for (int mt=0; mt<2; mt++){
    #pragma unroll
    for (int j=0; j<3; j++){
      int x = (wv*3 + j)*16 + lr;
      #pragma unroll
      for (int r=0; r<4; r++){
        int m = mt*16 + lq*4 + r;
        unsigned short h,l; split_bf(acc1[mt][j][r], h, l);
        LB[GH + x*40 + m] = h;
        LB[GL + x*40 + m] = l;
      }
    }
  }
  __syncthreads();

  // ---- GEMM-2: C2[x=192][y=144] = G x Tiy, K=32 ----
  f32x4 acc2[3][9] = {};
  short8 tyh[9], tyl[9];
  #pragma unroll
  for (int yt=0; yt<9; yt++){
    tyh[yt] = *(const short8*)&LB[TIYHo + (yt*16+lr)*40 + lq*8];
    tyl[yt] = *(const short8*)&LB[TIYLo + (yt*16+lr)*40 + lq*8];
  }
  #pragma unroll
  for (int i=0; i<3; i++){
    int x = (wv*3 + i)*16 + lr;
    short8 gh = *(const short8*)&LB[GH + x*40 + lq*8];
    short8 gl = *(const short8*)&LB[GL + x*40 + lq*8];
    #pragma unroll
    for (int yt=0; yt<9; yt++){
      acc2[i][yt] = __builtin_amdgcn_mfma_f32_16x16x32_bf16(gh, tyh[yt], acc2[i][yt], 0,0,0);
      acc2[i][yt] = __builtin_amdgcn_mfma_f32_16x16x32_bf16(gl, tyh[yt], acc2[i][yt], 0,0,0);
      acc2[i][yt] = __builtin_amdgcn_mfma_f32_16x16x32_bf16(gh, tyl[yt], acc2[i][yt], 0,0,0);
    }
  }

  // ---- masked stats over valid region ----
  float s = 0.f, ss = 0.f;
  #pragma unroll
  for (int i=0; i<3; i++){
    int xt = wv*3 + i;
    #pragma unroll
    for (int yt=0; yt<9; yt++){
      #pragma unroll
      for (int r=0; r<4; r++){
        int x = xt*16 + lq*4 + r;
        int y = yt*16 + lr;
        if (x < SX && y < SY){
          float v = acc2[i][yt][r];
          s += v; ss += v*v;
        }
      }
    }
  }
  for (int off = 32; off >= 1; off >>= 1){ s += __shfl_down(s,off); ss += __shfl_down(ss,off); }
  if (lane == 0){ sred[0][wv] = s; sred[1][wv] = ss; }
  __syncthreads();
  if (t == 0){
    float S = sred[0][0]+sred[0][1]+sred[0][2]+sred[0][3];
    float SS = sred[1][0]+sred[1][1]+sred[1][2]+sred[1][3];
    float mean = S * (1.0f/IMG);
    float var  = SS * (1.0f/IMG) - mean*mean;
    mb[0] = mean; mb[1] = rsqrtf(var + 1e-5f);
  }
  __syncthreads();
  float mean = mb[0], istd = mb[1];

  unsigned short* dst = (LAYER == 0) ? (A1 + (size_t)bid*IMG)
                                     : (Abf + (size_t)b*KPAD + (size_t)o*IMG);
  #pragma unroll
  for (int i=0; i<3; i++){
    int xt = wv*3 + i;
    #pragma unroll
    for (int yt=0; yt<9; yt++){
      #pragma unroll
      for (int r=0; r<4; r++){
        int x = xt*16 + lq*4 + r;
        int y = yt*16 + lr;
        if (x < SX && y < SY){
          float v = (acc2[i][yt][r] - mean) * istd;
          dst[x*SY + y] = f2bf(gelu_f(v));
        }
      }
    }
  }
}

// ================= W fp32 -> bf16 (padded to KPAD) =================
__global__ void k_cvt_w(const float* __restrict__ W, unsigned short* __restrict__ Wbf){
  int row = blockIdx.y;
  int gi = blockIdx.x*256 + threadIdx.x;
  if (gi >= KPAD/8) return;
  unsigned short* dst = Wbf + (size_t)row*KPAD + gi*8;
  if (gi*8 >= FLATK){
    *(ushort4*)dst = make_ushort4(0,0,0,0);
    *(ushort4*)(dst+4) = make_ushort4(0,0,0,0);
    return;
  }
  const float4* src = (const float4*)(W + (size_t)row*FLATK + gi*8);
  float4 v0 = src[0], v1 = src[1];
  ushort4 u0, u1;
  u0.x=f2bf(v0.x); u0.y=f2bf(v0.y); u0.z=f2bf(v0.z); u0.w=f2bf(v0.w);
  u1.x=f2bf(v1.x); u1.y=f2bf(v1.y); u1.z=f2bf(v1.z); u1.w=f2bf(v1.w);
  *(ushort4*)dst = u0;
  *(ushort4*)(dst+4) = u1;
}

// ================= zero-pad Abf k-tail =================
__global__ void k_padA(unsigned short* __restrict__ Abf){
  int t = blockIdx.x*256 + threadIdx.x;
  if (t >= B_*2) return;
  int b = t >> 1, h = t & 1;
  *(ushort4*)&Abf[(size_t)b*KPAD + FLATK + h*4] = make_ushort4(0,0,0,0);
}

// ================= big GEMM: 128x128 tile, BK=32, global_load_lds, split-K =================
__global__ __launch_bounds__(256) void k_gemm_fast(const unsigned short* __restrict__ Abf,
                                                   const unsigned short* __restrict__ Wbf,
                                                   float* __restrict__ Cpart){
  __shared__ unsigned short As[128*32];
  __shared__ unsigned short Bs[128*32];
  int t = threadIdx.x;
  int bx = blockIdx.x, by = blockIdx.y, kz = blockIdx.z;
  int ks0 = kz*KCH, ks1 = min(ks0 + KCH, KSTEPS);
  int lane = t & 63, wv = t >> 6;
  int lr = lane & 15, lq = lane >> 4;
  int wr = wv >> 1, wc = wv & 1;
  int srow = t >> 2, scol = (t & 3) * 8;
  const unsigned short* ga0 = Abf + (size_t)(bx*128 + srow)*KPAD + scol;
  const unsigned short* ga1 = ga0 + (size_t)64*KPAD;
  int wrow0 = min(by*128 + srow, HID1-1);
  int wrow1 = min(by*128 + 64 + srow, HID1-1);
  const unsigned short* gb0 = Wbf + (size_t)wrow0*KPAD + scol;
  const unsigned short* gb1 = Wbf + (size_t)wrow1*KPAD + scol;
  unsigned short* la0 = &As[srow*32 + scol];
  unsigned short* la1 = &As[(64+srow)*32 + scol];
  unsigned short* lb0 = &Bs[srow*32 + scol];
  unsigned short* lb1 = &Bs[(64+srow)*32 + scol];
  f32x4 acc[4][4] = {};
  for (int ks = ks0; ks < ks1; ks++){
    size_t gk = (size_t)ks*32;
    gl_lds16(ga0 + gk, la0);
    gl_lds16(ga1 + gk, la1);
    gl_lds16(gb0 + gk, lb0);
    gl_lds16(gb1 + gk, lb1);
    __syncthreads();
    short8 a[4], b[4];
    #pragma unroll
    for (int m = 0; m < 4; m++)
      a[m] = *(const short8*)&As[(wr*64 + m*16 + lr)*32 + lq*8];
    #pragma unroll
    for (int n = 0; n < 4; n++)
      b[n] = *(const short8*)&Bs[(wc*64 + n*16 + lr)*32 + lq*8];
    #pragma unroll
    for (int m = 0; m < 4; m++){
      #pragma unroll
      for (int n = 0; n < 4; n++){
        acc[m][n] = __builtin_amdgcn_mfma_f32_16x16x32_bf16(a[m], b[n], acc[m][n], 0, 0, 0);
      }
    }
    __syncthreads();
  }
  float* Cp = Cpart + (size_t)kz*B_*H1STR;
  #pragma unroll
  for (int m = 0; m < 4; m++){
    int grow = bx*128 + wr*64 + m*16 + lq*4;
    #pragma unroll
    for (int n = 0; n < 4; n++){
      int gcol = by*128 + wc*64 + n*16 + lr;
      #pragma unroll
      for (int r = 0; r < 4; r++)
        Cp[(size_t)(grow + r)*H1STR + gcol] = acc[m][n][r];
    }
  }
}

// ================= split-K reduce + bias + relu =================
__global__ void k_red(const float* __restrict__ Cp, const float* __restrict__ bias,
                      float* __restrict__ h1){
  size_t idx = (size_t)(blockIdx.x*256 + threadIdx.x)*4;
  if (idx >= (size_t)B_*H1STR) return;
  int col = (int)(idx % H1STR);
  float4 a = *(const float4*)(Cp + idx);
  float4 b = *(const float4*)(Cp + (size_t)B_*H1STR + idx);
  float4 c = *(const float4*)(Cp + (size_t)2*B_*H1STR + idx);
  float4 d = *(const float4*)(Cp + (size_t)3*B_*H1STR + idx);
  float4 o;
  o.x = fmaxf(a.x+b.x+c.x+d.x + ((col+0)<HID1 ? bias[col+0] : 0.f), 0.f);
  o.y = fmaxf(a.y+b.y+c.y+d.y + ((col+1)<HID1 ? bias[col+1] : 0.f), 0.f);
  o.z = fmaxf(a.z+b.z+c.z+d.z + ((col+2)<HID1 ? bias[col+2] : 0.f), 0.f);
  o.w = fmaxf(a.w+b.w+c.w+d.w + ((col+3)<HID1 ? bias[col+3] : 0.f), 0.f);
  *(float4*)(h1 + idx) = o;
}

// ================= out1 layer 2 =================
__global__ __launch_bounds__(256) void k_gemm2(const float* __restrict__ h1,
                                               const float* __restrict__ w2,
                                               const float* __restrict__ b2,
                                               float* __restrict__ o1){
  __shared__ float hs[16][68];
  __shared__ float wsm[16][68];
  int t = threadIdx.x;
  int bx = blockIdx.x, by = blockIdx.y;
  int r = t >> 4, c4 = (t & 15) * 4;
  int bi = t >> 4, oi = t & 15;
  float acc = 0.f;
  for (int ks = 0; ks < 44; ks++){
    int gk = ks*64 + c4;
    float4 va = make_float4(0.f,0.f,0.f,0.f);
    if (gk < HID1) va = *(const float4*)&h1[(size_t)(bx*16 + r)*H1STR + gk];
    *(float4*)&hs[r][c4] = va;
    int go = by*16 + r;
    float4 vb = make_float4(0.f,0.f,0.f,0.f);
    if (gk < HID1 && go < NOUT) vb = *(const float4*)&w2[(size_t)go*HID1 + gk];
    *(float4*)&wsm[r][c4] = vb;
    __syncthreads();
    #pragma unroll 8
    for (int k = 0; k < 64; k++) acc += hs[bi][k] * wsm[oi][k];
    __syncthreads();
  }
  int go = by*16 + oi;
  if (go < NOUT) o1[(size_t)(bx*16 + bi)*NOUT + go] = acc + b2[go];
}

// ================= final reg2 MLP =================
__global__ void k_reg2(const float* __restrict__ o1, const float* __restrict__ xin,
                       const float* __restrict__ w1, const float* __restrict__ b1,
                       const float* __restrict__ w2, const float* __restrict__ b2,
                       float* __restrict__ outp){
  __shared__ float s[360];
  __shared__ float tt[180];
  int b = blockIdx.x, t = threadIdx.x;
  if (t < 180){
    s[2*t]   = o1[b*NOUT + t];
    s[2*t+1] = (xin[(size_t)b*SX*XROW + t*XROW + (XROW-1)] - 400.0f) * 0.01f;
  }
  __syncthreads();
  if (t < 180){
    float a = b1[t];
    for (int j = 0; j < 360; j++) a += s[j] * w1[t*360 + j];
    tt[t] = fmaxf(a, 0.0f);
  }
  __syncthreads();
  if (t < 180){
    float a = b2[t];
    for (int j = 0; j < 180; j++) a += tt[j] * w2[t*180 + j];
    outp[b*NOUT + t] = a*100.0f + 400.0f;
  }
}

extern "C" void kernel_launch(void* const* d_in, const int* in_sizes, int n_in,
                              void* d_out, int out_size, void* d_ws, size_t ws_size,
                              hipStream_t stream){
  const float* xin   = (const float*)d_in[0];
  const float* wA0   = (const float*)d_in[1];
  const float* wB0   = (const float*)d_in[2];
  const float* wA1   = (const float*)d_in[3];
  const float* wB1   = (const float*)d_in[4];
  const float* o1w1  = (const float*)d_in[5];
  const float* o1b1  = (const float*)d_in[6];
  const float* o1w2  = (const float*)d_in[7];
  const float* o1b2  = (const float*)d_in[8];
  const float* r2w1  = (const float*)d_in[9];
  const float* r2b1  = (const float*)d_in[10];
  const float* r2w2  = (const float*)d_in[11];
  const float* r2b2  = (const float*)d_in[12];
  float* ws  = (float*)d_ws;
  float* out = (float*)d_out;

  // ---- table region (shorts within float-slot region [0, 38400)) ----
  unsigned short* tab = (unsigned short*)ws;
  unsigned short *TyH = tab,            *TyL = tab + TY_SH;
  unsigned short *TxH = TyL + TY_SH,    *TxL = TxH + TX_SH;
  unsigned short *TxiH = TxL + TX_SH,   *TxiL = TxiH + TXI_SH;
  unsigned short *TiyH = TxiL + TXI_SH, *TiyL = TiyH + TIY_SH;   // end 76800 sh = 38400 f

  size_t oU1  = 38400;
  size_t oUg  = oU1  + (size_t)B_*2048;
  size_t oU2  = oUg  + 4096;
  size_t oA1  = oU2  + (size_t)3072*2048;
  size_t oAbf = oA1  + (size_t)3072*IMG/2;
  size_t oWbf = oAbf + (size_t)B_*KPAD/2;
  size_t oCp  = oWbf + (size_t)HID1*KPAD/2;
  size_t oH1  = oCp  + (size_t)4*B_*H1STR;
  size_t oO1  = oH1  + (size_t)B_*H1STR;

  float *U1 = ws + oU1, *Ug = ws + oUg, *U2 = ws + oU2;
  unsigned short *A1  = (unsigned short*)(ws + oA1);
  unsigned short *Abf = (unsigned short*)(ws + oAbf);
  unsigned short *Wbf = (unsigned short*)(ws + oWbf);
  float *Cpart = ws + oCp, *H1 = ws + oH1, *O1 = ws + oO1;

  k_tables2<<<54, 256, 0, stream>>>(TyH, TyL, TxH, TxL, TxiH, TxiL, TiyH, TiyL);

  // layer 1
  k_fwd<0><<<B_ + 2, 256, 0, stream>>>(xin, nullptr, TyH, TyL, TxH, TxL, U1, Ug);
  k_inv<0><<<3072, 256, 0, stream>>>(U1, Ug, nullptr, wA0, wB0, TxiH, TxiL, TiyH, TiyL, A1, nullptr);
  // layer 2
  k_fwd<1><<<3072, 256, 0, stream>>>(nullptr, A1, TyH, TyL, TxH, TxL, U2, nullptr);
  k_inv<1><<<3072, 256, 0, stream>>>(nullptr, nullptr, U2, wA1, wB1, TxiH, TxiL, TiyH, TiyL, nullptr, Abf);

  // head
  k_padA<<<8, 256, 0, stream>>>(Abf);
  k_cvt_w<<<dim3(35, HID1), 256, 0, stream>>>(o1w1, Wbf);
  k_gemm_fast<<<dim3(8, 22, 4), 256, 0, stream>>>(Abf, Wbf, Cpart);
  k_red<<<(B_*H1STR/4 + 255)/256, 256, 0, stream>>>(Cpart, o1b1, H1);
  k_gemm2<<<dim3(64, 12), 256, 0, stream>>>(H1, o1w2, o1b2, O1);
  k_reg2<<<B_, 192, 0, stream>>>(O1, xin, r2w1, r2b1, r2w2, r2b2, out);
}

// Round 6
// 1602.640 us; speedup vs baseline: 7.6259x; 1.1215x over previous
//
#include <hip/hip_runtime.h>
#include <hip/hip_bf16.h>
#include <math.h>

#ifndef M_PI
#define M_PI 3.14159265358979323846
#endif

#define B_    1024
#define SX    180
#define SY    130
#define NC    3
#define IMG   23400
#define FLATK 70200
#define KPAD  70208
#define HID1  2808
#define NOUT  180
#define XROW  131
#define H1STR 2816
#define KSTEPS 2194   // KPAD/32
#define KCH    549    // ceil(KSTEPS/4)

typedef __attribute__((ext_vector_type(8))) short short8;
typedef __attribute__((ext_vector_type(4))) float f32x4;
typedef __attribute__((address_space(3))) unsigned int lds_u32;
typedef __attribute__((address_space(1))) const unsigned int glb_u32;

// padded table sizes (shorts) — ALL staging loop trip counts must be %64==0
#define TY_SH   5632   // 32*168=5376 -> pad 5632  (704 iters)
#define TX_SH   12800  // 64*200           (1600 iters, already %64==0)
#define TXI_SH  13824  // 192*72           (1728 iters, %64==0)
#define TIY_SH  6144   // 144*40=5760 -> pad 6144 (768 iters)

__device__ __forceinline__ unsigned short f2bf(float f){
  __hip_bfloat16 h = __float2bfloat16(f);
  return __builtin_bit_cast(unsigned short, h);
}
__device__ __forceinline__ float bf2f(unsigned short u){
  __hip_bfloat16 h = __builtin_bit_cast(__hip_bfloat16, u);
  return __bfloat162float(h);
}
__device__ __forceinline__ void split_bf(float f, unsigned short &hi, unsigned short &lo){
  hi = f2bf(f);
  lo = f2bf(f - bf2f(hi));
}
__device__ __forceinline__ void gl_lds16(const void* g, void* l){
  __builtin_amdgcn_global_load_lds((glb_u32*)g, (lds_u32*)l, 16, 0, 0);
}
__device__ __forceinline__ float gelu_f(float v){
  return 0.5f * v * (1.0f + erff(v * 0.70710678118654752f));
}

// ================= tables (split hi/lo bf16, LDS-matching strides, padded) =================
__global__ void k_tables2(unsigned short* __restrict__ TyH, unsigned short* __restrict__ TyL,
                          unsigned short* __restrict__ TxH, unsigned short* __restrict__ TxL,
                          unsigned short* __restrict__ TxiH, unsigned short* __restrict__ TxiL,
                          unsigned short* __restrict__ TiyH, unsigned short* __restrict__ TiyL){
  int i = blockIdx.x*256 + threadIdx.x;
  unsigned short h, l;
  if (i < TY_SH){
    int m = i/168, y = i%168;
    float v = 0.f;
    if (m < 32 && y < SY){
      int ky = m>>1, ri = m&1;
      double ang = 2.0*M_PI*(double)((ky*y)%SY)/(double)SY;
      v = ri ? (float)(-sin(ang)) : (float)cos(ang);
    }
    split_bf(v,h,l); TyH[i]=h; TyL[i]=l;
  }
  if (i < TX_SH){
    int n = i/200, x = i%200;
    float v = 0.f;
    if (x < SX){
      int kxi = n>>1, ri = n&1;
      int kx = (kxi<16)? kxi : kxi+148;
      double ang = 2.0*M_PI*(double)((kx*x)%SX)/(double)SX;
      v = ri ? (float)sin(ang) : (float)cos(ang);
    }
    split_bf(v,h,l); TxH[i]=h; TxL[i]=l;
  }
  if (i < TXI_SH){
    int x = i/72, k = i%72;
    float v = 0.f;
    if (x < SX && k < 64){
      int kxi = k>>1, ri = k&1;
      int kx = (kxi<16)? kxi : kxi+148;
      double ang = 2.0*M_PI*(double)((kx*x)%SX)/(double)SX;
      v = (float)((ri ? sin(ang) : cos(ang)) / (double)SX);
    }
    split_bf(v,h,l); TxiH[i]=h; TxiL[i]=l;
  }
  if (i < TIY_SH){
    int y = i/40, m = i%40;
    float v = 0.f;
    if (y < SY && m < 32){
      int ky = m>>1, ri = m&1;
      if (m == 0) v = 1.0f/(float)SY;
      else if (m == 1) v = 0.f;
      else {
        double ang = 2.0*M_PI*(double)((ky*y)%SY)/(double)SY;
        v = (float)((ri ? -2.0*sin(ang) : 2.0*cos(ang)) / (double)SY);
      }
    }
    split_bf(v,h,l); TiyH[i]=h; TiyL[i]=l;
  }
}

// ================= fused fwd: stats + fwd_y MFMA + fwd_x MFMA =================
// SRC 0: layer1, input xin fp32 (bid<B_: data ch of batch bid; bid==B_: gridx; B_+1: gridy)
// SRC 1: layer2, input A1 bf16, block = bc
template<int SRC>
__global__ __launch_bounds__(256) void k_fwd(const float* __restrict__ xin,
                                             const unsigned short* __restrict__ A1,
                                             const unsigned short* __restrict__ TyH,
                                             const unsigned short* __restrict__ TyL,
                                             const unsigned short* __restrict__ TxH,
                                             const unsigned short* __restrict__ TxL,
                                             float* __restrict__ Uout,
                                             float* __restrict__ Ug){
  constexpr int DHI = 0;
  constexpr int DLO = (SRC==0) ? 32256 : 0;                 // SRC1: unused
  constexpr int TYHo = (SRC==0) ? 64512 : 32256;
  constexpr int TYLo = TYHo + TY_SH;
  constexpr int LDSN = TYLo + TY_SH;                        // SRC0: 75776, SRC1: 43520
  constexpr int YTH = 0, YTL = 6400, TXHo = 12800, TXLo = 25600;  // phase-2 regions (<=38400)
  __shared__ unsigned short LB[LDSN];
  __shared__ float sred[2][4];
  __shared__ float mb[2];
  int t = threadIdx.x, lane = t&63, wv = t>>6, lr = lane&15, lq = lane>>4;
  int bid = blockIdx.x;

  // ---- stage Ty tables (async, full-wave trip counts) ----
  for (int i=t; i<TY_SH/8; i+=256) gl_lds16(TyH + i*8, &LB[TYHo + i*8]);
  for (int i=t; i<TY_SH/8; i+=256) gl_lds16(TyL + i*8, &LB[TYLo + i*8]);

  // ---- stage data rows [192][K=160, stride 168] + stats ----
  float s = 0.f, ss = 0.f;
  for (int i=t; i<7680; i+=256){
    int row = i/40, c4 = (i - row*40)*4;
    if (SRC == 0){
      float v[4];
      #pragma unroll
      for (int j=0;j<4;j++){
        int y = c4 + j;
        float val = 0.f;
        if (row < SX && y < SY){
          if (bid < B_)       val = xin[(size_t)bid*(SX*XROW) + row*XROW + y];
          else if (bid == B_) val = (float)row * (1.0f/179.0f);
          else                val = (float)y * (1.0f/129.0f);
        }
        s += val; ss += val*val;
        v[j] = val;
      }
      unsigned short h0,l0,h1,l1,h2,l2,h3,l3;
      split_bf(v[0],h0,l0); split_bf(v[1],h1,l1); split_bf(v[2],h2,l2); split_bf(v[3],h3,l3);
      *(ushort4*)&LB[DHI + row*168 + c4] = make_ushort4(h0,h1,h2,h3);
      *(ushort4*)&LB[DLO + row*168 + c4] = make_ushort4(l0,l1,l2,l3);
    } else {
      ushort4 d = make_ushort4(0,0,0,0);
      if (row < SX){
        const unsigned short* src = A1 + (size_t)bid*IMG + row*SY + c4;
        if (c4 <= 124){
          ushort2 a = *(const ushort2*)src;
          ushort2 b = *(const ushort2*)(src+2);
          d.x=a.x; d.y=a.y; d.z=b.x; d.w=b.y;
        } else if (c4 == 128){
          ushort2 a = *(const ushort2*)src;
          d.x=a.x; d.y=a.y;
        }
      }
      float v0=bf2f(d.x), v1=bf2f(d.y), v2=bf2f(d.z), v3=bf2f(d.w);
      s += v0+v1+v2+v3; ss += v0*v0+v1*v1+v2*v2+v3*v3;
      *(ushort4*)&LB[DHI + row*168 + c4] = d;
    }
  }
  // ---- block stats reduce ----
  for (int o = 32; o >= 1; o >>= 1){ s += __shfl_down(s,o); ss += __shfl_down(ss,o); }
  if (lane == 0){ sred[0][wv] = s; sred[1][wv] = ss; }
  __syncthreads();
  if (t == 0){
    float S = sred[0][0]+sred[0][1]+sred[0][2]+sred[0][3];
    float SS = sred[1][0]+sred[1][1]+sred[1][2]+sred[1][3];
    float mean = S * (1.0f/IMG);
    float var  = SS * (1.0f/IMG) - mean*mean;
    mb[0] = mean; mb[1] = rsqrtf(var + 1e-5f);
  }
  __syncthreads();

  // ---- phase 1: C1[m=32][x=192] = Ty x D, K=160 ----
  f32x4 acc[2][3] = {};
  #pragma unroll
  for (int ks=0; ks<5; ks++){
    short8 tyh[2], tyl[2];
    #pragma unroll
    for (int mt=0; mt<2; mt++){
      tyh[mt] = *(const short8*)&LB[TYHo + (mt*16+lr)*168 + ks*32 + lq*8];
      tyl[mt] = *(const short8*)&LB[TYLo + (mt*16+lr)*168 + ks*32 + lq*8];
    }
    #pragma unroll
    for (int j=0; j<3; j++){
      int xr = (wv*3 + j)*16 + lr;
      short8 dh = *(const short8*)&LB[DHI + xr*168 + ks*32 + lq*8];
      #pragma unroll
      for (int mt=0; mt<2; mt++){
        acc[mt][j] = __builtin_amdgcn_mfma_f32_16x16x32_bf16(tyh[mt], dh, acc[mt][j], 0,0,0);
        acc[mt][j] = __builtin_amdgcn_mfma_f32_16x16x32_bf16(tyl[mt], dh, acc[mt][j], 0,0,0);
      }
      if (SRC == 0){
        short8 dl = *(const short8*)&LB[DLO + xr*168 + ks*32 + lq*8];
        #pragma unroll
        for (int mt=0; mt<2; mt++)
          acc[mt][j] = __builtin_amdgcn_mfma_f32_16x16x32_bf16(tyh[mt], dl, acc[mt][j], 0,0,0);
      }
    }
  }
  __syncthreads();   // all phase-1 LDS reads done before overwrite

  // ---- stage Tx (async, full-wave) + write Yt split-bf16 [m][200] ----
  for (int i=t; i<TX_SH/8; i+=256) gl_lds16(TxH + i*8, &LB[TXHo + i*8]);
  for (int i=t; i<TX_SH/8; i+=256) gl_lds16(TxL + i*8, &LB[TXLo + i*8]);
  {
    float mean = mb[0], istd = mb[1];
    #pragma unroll
    for (int mt=0; mt<2; mt++){
      #pragma unroll
      for (int j=0; j<3; j++){
        int xr = (wv*3 + j)*16 + lr;
        #pragma unroll
        for (int r=0; r<4; r++){
          int m = mt*16 + lq*4 + r;
          float v = acc[mt][j][r];
          if (m == 0) v -= 130.0f*mean;
          v *= istd;
          unsigned short h,l; split_bf(v,h,l);
          LB[YTH + m*200 + xr] = h;
          LB[YTL + m*200 + xr] = l;
        }
      }
    }
  }
  __syncthreads();

  // ---- phase 2: U[m=32][n=64] = Yt x Tx, K=192 ----
  f32x4 acc2[2] = {};
  #pragma unroll
  for (int ks=0; ks<6; ks++){
    short8 txh = *(const short8*)&LB[TXHo + (wv*16+lr)*200 + ks*32 + lq*8];
    short8 txl = *(const short8*)&LB[TXLo + (wv*16+lr)*200 + ks*32 + lq*8];
    #pragma unroll
    for (int mt=0; mt<2; mt++){
      short8 yh = *(const short8*)&LB[YTH + (mt*16+lr)*200 + ks*32 + lq*8];
      short8 yl = *(const short8*)&LB[YTL + (mt*16+lr)*200 + ks*32 + lq*8];
      acc2[mt] = __builtin_amdgcn_mfma_f32_16x16x32_bf16(yh, txh, acc2[mt], 0,0,0);
      acc2[mt] = __builtin_amdgcn_mfma_f32_16x16x32_bf16(yl, txh, acc2[mt], 0,0,0);
      acc2[mt] = __builtin_amdgcn_mfma_f32_16x16x32_bf16(yh, txl, acc2[mt], 0,0,0);
    }
  }
  float* Ub;
  if (SRC == 1) Ub = Uout + (size_t)bid*2048;
  else Ub = (bid < B_) ? (Uout + (size_t)bid*2048) : (Ug + (size_t)(bid - B_)*2048);
  #pragma unroll
  for (int mt=0; mt<2; mt++){
    #pragma unroll
    for (int r=0; r<4; r++){
      int m = mt*16 + lq*4 + r;
      int n = wv*16 + lr;
      Ub[m*64 + n] = acc2[mt][r];
    }
  }
}

// ================= fused inv: mix + inv_x MFMA + inv_y MFMA + norm + gelu =================
template<int LAYER>
__global__ __launch_bounds__(256) void k_inv(const float* __restrict__ U1,
                                             const float* __restrict__ Ug,
                                             const float* __restrict__ U2,
                                             const float* __restrict__ w1,
                                             const float* __restrict__ w2,
                                             const unsigned short* __restrict__ TxiH,
                                             const unsigned short* __restrict__ TxiL,
                                             const unsigned short* __restrict__ TiyH,
                                             const unsigned short* __restrict__ TiyL,
                                             unsigned short* __restrict__ A1,
                                             unsigned short* __restrict__ Abf){
  constexpr int TXIHo = 0, TXILo = TXI_SH;                  // 0, 13824
  constexpr int TIYHo = TXILo + TXI_SH;                     // 27648
  constexpr int TIYLo = TIYHo + TIY_SH;                     // 33792
  constexpr int ZFH = TIYLo + TIY_SH;                       // 39936
  constexpr int ZFL = ZFH + 2304;                           // 42240
  constexpr int GH  = ZFL + 2304;                           // 44544
  constexpr int GL  = GH + 7680;                            // 52224 -> end 59904
  __shared__ unsigned short LB[59904];
  __shared__ float sred[2][4];
  __shared__ float mb[2];
  int t = threadIdx.x, lane = t&63, wv = t>>6, lr = lane&15, lq = lane>>4;
  int bid = blockIdx.x, b = bid/3, o = bid - b*3;

  for (int i=t; i<TXI_SH/8; i+=256) gl_lds16(TxiH + i*8, &LB[TXIHo + i*8]);
  for (int i=t; i<TXI_SH/8; i+=256) gl_lds16(TxiL + i*8, &LB[TXILo + i*8]);
  for (int i=t; i<TIY_SH/8; i+=256) gl_lds16(TiyH + i*8, &LB[TIYHo + i*8]);
  for (int i=t; i<TIY_SH/8; i+=256) gl_lds16(TiyL + i*8, &LB[TIYLo + i*8]);

  // ---- mix -> Zfold split-bf16 [32][72] ----
  #pragma unroll
  for (int pp=0; pp<2; pp++){
    int p = t + pp*256;
    int kxi = p & 31, ky = p >> 5;
    const float* w = (kxi < 16) ? w1 : w2;
    int kxm = kxi & 15;
    float ar = 0.f, ai = 0.f;
    #pragma unroll
    for (int i=0; i<3; i++){
      const float* Ui;
      if (LAYER == 0) Ui = (i==0) ? (U1 + (size_t)b*2048) : (Ug + (size_t)(i-1)*2048);
      else            Ui = U2 + ((size_t)b*3 + i)*2048;
      float P = Ui[(2*ky  )*64 + 2*kxi  ];
      float Q = Ui[(2*ky  )*64 + 2*kxi+1];
      float R = Ui[(2*ky+1)*64 + 2*kxi  ];
      float S = Ui[(2*ky+1)*64 + 2*kxi+1];
      float zr = P + S, zi = R - Q;
      size_t wo = ((((size_t)i*3 + o)*16 + kxm)*16 + ky)*2;
      float wr = w[wo], wi = w[wo+1];
      ar += zr*wr - zi*wi;
      ai += zr*wi + zi*wr;
    }
    unsigned short hr,lr_, hi,li, hn,ln;
    split_bf(ar,hr,lr_); split_bf(ai,hi,li); split_bf(-ai,hn,ln);
    LB[ZFH + (2*ky  )*72 + 2*kxi  ] = hr;  LB[ZFL + (2*ky  )*72 + 2*kxi  ] = lr_;
    LB[ZFH + (2*ky  )*72 + 2*kxi+1] = hn;  LB[ZFL + (2*ky  )*72 + 2*kxi+1] = ln;
    LB[ZFH + (2*ky+1)*72 + 2*kxi  ] = hi;  LB[ZFL + (2*ky+1)*72 + 2*kxi  ] = li;
    LB[ZFH + (2*ky+1)*72 + 2*kxi+1] = hr;  LB[ZFL + (2*ky+1)*72 + 2*kxi+1] = lr_;
  }
  __syncthreads();

  // ---- GEMM-1: C1[m=32][x=192] = Zfold x Txi, K=64 ----
  f32x4 acc1[2][3] = {};
  #pragma unroll
  for (int ks=0; ks<2; ks++){
    short8 zh[2], zl[2];
    #pragma unroll
    for (int mt=0; mt<2; mt++){
      zh[mt] = *(const short8*)&LB[ZFH + (mt*16+lr)*72 + ks*32 + lq*8];
      zl[mt] = *(const short8*)&LB[ZFL + (mt*16+lr)*72 + ks*32 + lq*8];
    }
    #pragma unroll
    for (int j=0; j<3; j++){
      int x = (wv*3 + j)*16 + lr;
      short8 txh = *(const short8*)&LB[TXIHo + x*72 + ks*32 + lq*8];
      short8 txl = *(const short8*)&LB[TXILo + x*72 + ks*32 + lq*8];
      #pragma unroll
      for (int mt=0; mt<2; mt++){
        acc1[mt][j] = __builtin_amdgcn_mfma_f32_16x16x32_bf16(zh[mt], txh, acc1[mt][j], 0,0,0);
        acc1[mt][j] = __builtin_amdgcn_mfma_f32_16x16x32_bf16(zl[mt], txh, acc1[mt][j], 0,0,0);
        acc1[mt][j] = __builtin_amdgcn_mfma_f32_16x16x32_bf16(zh[mt], txl, acc1[mt][j], 0,0,0);
      }
    }
  }
  // ---- write G^T split-bf16 [x=192][40] (disjoint region; barrier before reads) ----
  #pragma unroll
  for (int mt=0; mt<2; mt++){
    #pragma unroll
    for (int j=0; j<3; j++){
      int x = (wv*3 + j)*16 + lr;
      #pragma unroll
      for (int r=0; r<4; r++){
        int m = mt*16 + lq*4 + r;
        unsigned short h,l; split_bf(acc1[mt][j][r], h, l);
        LB[GH + x*40 + m] = h;
        LB[GL + x*40 + m] = l;
      }
    }
  }
  __syncthreads();

  // ---- GEMM-2: C2[x=192][y=144] = G x Tiy, K=32 ----
  f32x4 acc2[3][9] = {};
  short8 tyh[9], tyl[9];
  #pragma unroll
  for (int yt=0; yt<9; yt++){
    tyh[yt] = *(const short8*)&LB[TIYHo + (yt*16+lr)*40 + lq*8];
    tyl[yt] = *(const short8*)&LB[TIYLo + (yt*16+lr)*40 + lq*8];
  }
  #pragma unroll
  for (int i=0; i<3; i++){
    int x = (wv*3 + i)*16 + lr;
    short8 gh = *(const short8*)&LB[GH + x*40 + lq*8];
    short8 gl = *(const short8*)&LB[GL + x*40 + lq*8];
    #pragma unroll
    for (int yt=0; yt<9; yt++){
      acc2[i][yt] = __builtin_amdgcn_mfma_f32_16x16x32_bf16(gh, tyh[yt], acc2[i][yt], 0,0,0);
      acc2[i][yt] = __builtin_amdgcn_mfma_f32_16x16x32_bf16(gl, tyh[yt], acc2[i][yt], 0,0,0);
      acc2[i][yt] = __builtin_amdgcn_mfma_f32_16x16x32_bf16(gh, tyl[yt], acc2[i][yt], 0,0,0);
    }
  }

  // ---- masked stats over valid region ----
  float s = 0.f, ss = 0.f;
  #pragma unroll
  for (int i=0; i<3; i++){
    int xt = wv*3 + i;
    #pragma unroll
    for (int yt=0; yt<9; yt++){
      #pragma unroll
      for (int r=0; r<4; r++){
        int x = xt*16 + lq*4 + r;
        int y = yt*16 + lr;
        if (x < SX && y < SY){
          float v = acc2[i][yt][r];
          s += v; ss += v*v;
        }
      }
    }
  }
  for (int off = 32; off >= 1; off >>= 1){ s += __shfl_down(s,off); ss += __shfl_down(ss,off); }
  if (lane == 0){ sred[0][wv] = s; sred[1][wv] = ss; }
  __syncthreads();
  if (t == 0){
    float S = sred[0][0]+sred[0][1]+sred[0][2]+sred[0][3];
    float SS = sred[1][0]+sred[1][1]+sred[1][2]+sred[1][3];
    float mean = S * (1.0f/IMG);
    float var  = SS * (1.0f/IMG) - mean*mean;
    mb[0] = mean; mb[1] = rsqrtf(var + 1e-5f);
  }
  __syncthreads();
  float mean = mb[0], istd = mb[1];

  unsigned short* dst = (LAYER == 0) ? (A1 + (size_t)bid*IMG)
                                     : (Abf + (size_t)b*KPAD + (size_t)o*IMG);
  #pragma unroll
  for (int i=0; i<3; i++){
    int xt = wv*3 + i;
    #pragma unroll
    for (int yt=0; yt<9; yt++){
      #pragma unroll
      for (int r=0; r<4; r++){
        int x = xt*16 + lq*4 + r;
        int y = yt*16 + lr;
        if (x < SX && y < SY){
          float v = (acc2[i][yt][r] - mean) * istd;
          dst[x*SY + y] = f2bf(gelu_f(v));
        }
      }
    }
  }
}

// ================= W fp32 -> bf16 (padded to KPAD) =================
__global__ void k_cvt_w(const float* __restrict__ W, unsigned short* __restrict__ Wbf){
  int row = blockIdx.y;
  int gi = blockIdx.x*256 + threadIdx.x;
  if (gi >= KPAD/8) return;
  unsigned short* dst = Wbf + (size_t)row*KPAD + gi*8;
  if (gi*8 >= FLATK){
    *(ushort4*)dst = make_ushort4(0,0,0,0);
    *(ushort4*)(dst+4) = make_ushort4(0,0,0,0);
    return;
  }
  const float4* src = (const float4*)(W + (size_t)row*FLATK + gi*8);
  float4 v0 = src[0], v1 = src[1];
  ushort4 u0, u1;
  u0.x=f2bf(v0.x); u0.y=f2bf(v0.y); u0.z=f2bf(v0.z); u0.w=f2bf(v0.w);
  u1.x=f2bf(v1.x); u1.y=f2bf(v1.y); u1.z=f2bf(v1.z); u1.w=f2bf(v1.w);
  *(ushort4*)dst = u0;
  *(ushort4*)(dst+4) = u1;
}

// ================= zero-pad Abf k-tail =================
__global__ void k_padA(unsigned short* __restrict__ Abf){
  int t = blockIdx.x*256 + threadIdx.x;
  if (t >= B_*2) return;
  int b = t >> 1, h = t & 1;
  *(ushort4*)&Abf[(size_t)b*KPAD + FLATK + h*4] = make_ushort4(0,0,0,0);
}

// ================= big GEMM: 128x128 tile, BK=32, dbuf + counted vmcnt + XCD swizzle =================
// grid: 704 linear. decode: xcd = lid%8 ensures all 8 bx-blocks of a (by,kz)
// group land on one XCD -> B-panel + A-slice reuse is L2-local.
__global__ __launch_bounds__(256) void k_gemm_fast(const unsigned short* __restrict__ Abf,
                                                   const unsigned short* __restrict__ Wbf,
                                                   float* __restrict__ Cpart){
  __shared__ unsigned short As[2][128*32];
  __shared__ unsigned short Bs[2][128*32];
  int t = threadIdx.x;
  int lid = blockIdx.x;
  int xcd = lid & 7, inner = lid >> 3;       // inner 0..87
  int gq = inner >> 3, bx = inner & 7;       // gq 0..10
  int g = gq*8 + xcd;                        // group 0..87
  int by = g >> 2, kz = g & 3;
  int ks0 = kz*KCH, ks1 = min(ks0 + KCH, KSTEPS);
  int lane = t & 63, wv = t >> 6;
  int lr = lane & 15, lq = lane >> 4;
  int wr = wv >> 1, wc = wv & 1;
  int srow = t >> 2, scol = (t & 3) * 8;
  const unsigned short* ga0 = Abf + (size_t)(bx*128 + srow)*KPAD + scol;
  const unsigned short* ga1 = ga0 + (size_t)64*KPAD;
  int wrow0 = min(by*128 + srow, HID1-1);
  int wrow1 = min(by*128 + 64 + srow, HID1-1);
  const unsigned short* gb0 = Wbf + (size_t)wrow0*KPAD + scol;
  const unsigned short* gb1 = Wbf + (size_t)wrow1*KPAD + scol;
  int lofs = srow*32 + scol;
  f32x4 acc[4][4] = {};

  // prologue: stage tile ks0 into buffer 0
  {
    size_t gk = (size_t)ks0*32;
    gl_lds16(ga0 + gk, &As[0][lofs]);
    gl_lds16(ga1 + gk, &As[0][2048 + lofs]);
    gl_lds16(gb0 + gk, &Bs[0][lofs]);
    gl_lds16(gb1 + gk, &Bs[0][2048 + lofs]);
  }
  int cur = 0;
  for (int ks = ks0; ks < ks1; ks++){
    if (ks + 1 < ks1){
      // issue next tile's loads BEFORE computing current -> they stay in
      // flight across both barriers (counted vmcnt, never drain to 0 in-loop)
      size_t gk = (size_t)(ks+1)*32;
      int nb = cur ^ 1;
      gl_lds16(ga0 + gk, &As[nb][lofs]);
      gl_lds16(ga1 + gk, &As[nb][2048 + lofs]);
      gl_lds16(gb0 + gk, &Bs[nb][lofs]);
      gl_lds16(gb1 + gk, &Bs[nb][2048 + lofs]);
      asm volatile("s_waitcnt vmcnt(4)" ::: "memory");   // oldest 4 (cur tile) landed
    } else {
      asm volatile("s_waitcnt vmcnt(0)" ::: "memory");
    }
    __builtin_amdgcn_s_barrier();          // all waves: buf[cur] ready
    short8 a[4], b[4];
    #pragma unroll
    for (int m = 0; m < 4; m++)
      a[m] = *(const short8*)&As[cur][(wr*64 + m*16 + lr)*32 + lq*8];
    #pragma unroll
    for (int n = 0; n < 4; n++)
      b[n] = *(const short8*)&Bs[cur][(wc*64 + n*16 + lr)*32 + lq*8];
    #pragma unroll
    for (int m = 0; m < 4; m++){
      #pragma unroll
      for (int n = 0; n < 4; n++){
        acc[m][n] = __builtin_amdgcn_mfma_f32_16x16x32_bf16(a[m], b[n], acc[m][n], 0, 0, 0);
      }
    }
    // compiler's lgkmcnt-wait before MFMA guarantees all ds_reads complete
    // by the time each wave reaches this barrier -> safe to overwrite next iter
    __builtin_amdgcn_s_barrier();
    cur ^= 1;
  }
  float* Cp = Cpart + (size_t)kz*B_*H1STR;
  #pragma unroll
  for (int m = 0; m < 4; m++){
    int grow = bx*128 + wr*64 + m*16 + lq*4;
    #pragma unroll
    for (int n = 0; n < 4; n++){
      int gcol = by*128 + wc*64 + n*16 + lr;
      #pragma unroll
      for (int r = 0; r < 4; r++)
        Cp[(size_t)(grow + r)*H1STR + gcol] = acc[m][n][r];
    }
  }
}

// ================= split-K reduce + bias + relu =================
__global__ void k_red(const float* __restrict__ Cp, const float* __restrict__ bias,
                      float* __restrict__ h1){
  size_t idx = (size_t)(blockIdx.x*256 + threadIdx.x)*4;
  if (idx >= (size_t)B_*H1STR) return;
  int col = (int)(idx % H1STR);
  float4 a = *(const float4*)(Cp + idx);
  float4 b = *(const float4*)(Cp + (size_t)B_*H1STR + idx);
  float4 c = *(const float4*)(Cp + (size_t)2*B_*H1STR + idx);
  float4 d = *(const float4*)(Cp + (size_t)3*B_*H1STR + idx);
  float4 o;
  o.x = fmaxf(a.x+b.x+c.x+d.x + ((col+0)<HID1 ? bias[col+0] : 0.f), 0.f);
  o.y = fmaxf(a.y+b.y+c.y+d.y + ((col+1)<HID1 ? bias[col+1] : 0.f), 0.f);
  o.z = fmaxf(a.z+b.z+c.z+d.z + ((col+2)<HID1 ? bias[col+2] : 0.f), 0.f);
  o.w = fmaxf(a.w+b.w+c.w+d.w + ((col+3)<HID1 ? bias[col+3] : 0.f), 0.f);
  *(float4*)(h1 + idx) = o;
}

// ================= out1 layer 2 =================
__global__ __launch_bounds__(256) void k_gemm2(const float* __restrict__ h1,
                                               const float* __restrict__ w2,
                                               const float* __restrict__ b2,
                                               float* __restrict__ o1){
  __shared__ float hs[16][68];
  __shared__ float wsm[16][68];
  int t = threadIdx.x;
  int bx = blockIdx.x, by = blockIdx.y;
  int r = t >> 4, c4 = (t & 15) * 4;
  int bi = t >> 4, oi = t & 15;
  float acc = 0.f;
  for (int ks = 0; ks < 44; ks++){
    int gk = ks*64 + c4;
    float4 va = make_float4(0.f,0.f,0.f,0.f);
    if (gk < HID1) va = *(const float4*)&h1[(size_t)(bx*16 + r)*H1STR + gk];
    *(float4*)&hs[r][c4] = va;
    int go = by*16 + r;
    float4 vb = make_float4(0.f,0.f,0.f,0.f);
    if (gk < HID1 && go < NOUT) vb = *(const float4*)&w2[(size_t)go*HID1 + gk];
    *(float4*)&wsm[r][c4] = vb;
    __syncthreads();
    #pragma unroll 8
    for (int k = 0; k < 64; k++) acc += hs[bi][k] * wsm[oi][k];
    __syncthreads();
  }
  int go = by*16 + oi;
  if (go < NOUT) o1[(size_t)(bx*16 + bi)*NOUT + go] = acc + b2[go];
}

// ================= final reg2 MLP =================
__global__ void k_reg2(const float* __restrict__ o1, const float* __restrict__ xin,
                       const float* __restrict__ w1, const float* __restrict__ b1,
                       const float* __restrict__ w2, const float* __restrict__ b2,
                       float* __restrict__ outp){
  __shared__ float s[360];
  __shared__ float tt[180];
  int b = blockIdx.x, t = threadIdx.x;
  if (t < 180){
    s[2*t]   = o1[b*NOUT + t];
    s[2*t+1] = (xin[(size_t)b*SX*XROW + t*XROW + (XROW-1)] - 400.0f) * 0.01f;
  }
  __syncthreads();
  if (t < 180){
    float a = b1[t];
    for (int j = 0; j < 360; j++) a += s[j] * w1[t*360 + j];
    tt[t] = fmaxf(a, 0.0f);
  }
  __syncthreads();
  if (t < 180){
    float a = b2[t];
    for (int j = 0; j < 180; j++) a += tt[j] * w2[t*180 + j];
    outp[b*NOUT + t] = a*100.0f + 400.0f;
  }
}

extern "C" void kernel_launch(void* const* d_in, const int* in_sizes, int n_in,
                              void* d_out, int out_size, void* d_ws, size_t ws_size,
                              hipStream_t stream){
  const float* xin   = (const float*)d_in[0];
  const float* wA0   = (const float*)d_in[1];
  const float* wB0   = (const float*)d_in[2];
  const float* wA1   = (const float*)d_in[3];
  const float* wB1   = (const float*)d_in[4];
  const float* o1w1  = (const float*)d_in[5];
  const float* o1b1  = (const float*)d_in[6];
  const float* o1w2  = (const float*)d_in[7];
  const float* o1b2  = (const float*)d_in[8];
  const float* r2w1  = (const float*)d_in[9];
  const float* r2b1  = (const float*)d_in[10];
  const float* r2w2  = (const float*)d_in[11];
  const float* r2b2  = (const float*)d_in[12];
  float* ws  = (float*)d_ws;
  float* out = (float*)d_out;

  // ---- table region (shorts within float-slot region [0, 38400)) ----
  unsigned short* tab = (unsigned short*)ws;
  unsigned short *TyH = tab,            *TyL = tab + TY_SH;
  unsigned short *TxH = TyL + TY_SH,    *TxL = TxH + TX_SH;
  unsigned short *TxiH = TxL + TX_SH,   *TxiL = TxiH + TXI_SH;
  unsigned short *TiyH = TxiL + TXI_SH, *TiyL = TiyH + TIY_SH;   // end 76800 sh = 38400 f

  size_t oU1  = 38400;
  size_t oUg  = oU1  + (size_t)B_*2048;
  size_t oU2  = oUg  + 4096;
  size_t oA1  = oU2  + (size_t)3072*2048;
  size_t oAbf = oA1  + (size_t)3072*IMG/2;
  size_t oWbf = oAbf + (size_t)B_*KPAD/2;
  size_t oCp  = oWbf + (size_t)HID1*KPAD/2;
  size_t oH1  = oCp  + (size_t)4*B_*H1STR;
  size_t oO1  = oH1  + (size_t)B_*H1STR;

  float *U1 = ws + oU1, *Ug = ws + oUg, *U2 = ws + oU2;
  unsigned short *A1  = (unsigned short*)(ws + oA1);
  unsigned short *Abf = (unsigned short*)(ws + oAbf);
  unsigned short *Wbf = (unsigned short*)(ws + oWbf);
  float *Cpart = ws + oCp, *H1 = ws + oH1, *O1 = ws + oO1;

  k_tables2<<<54, 256, 0, stream>>>(TyH, TyL, TxH, TxL, TxiH, TxiL, TiyH, TiyL);

  // layer 1
  k_fwd<0><<<B_ + 2, 256, 0, stream>>>(xin, nullptr, TyH, TyL, TxH, TxL, U1, Ug);
  k_inv<0><<<3072, 256, 0, stream>>>(U1, Ug, nullptr, wA0, wB0, TxiH, TxiL, TiyH, TiyL, A1, nullptr);
  // layer 2
  k_fwd<1><<<3072, 256, 0, stream>>>(nullptr, A1, TyH, TyL, TxH, TxL, U2, nullptr);
  k_inv<1><<<3072, 256, 0, stream>>>(nullptr, nullptr, U2, wA1, wB1, TxiH, TxiL, TiyH, TiyL, nullptr, Abf);

  // head
  k_padA<<<8, 256, 0, stream>>>(Abf);
  k_cvt_w<<<dim3(35, HID1), 256, 0, stream>>>(o1w1, Wbf);
  k_gemm_fast<<<704, 256, 0, stream>>>(Abf, Wbf, Cpart);
  k_red<<<(B_*H1STR/4 + 255)/256, 256, 0, stream>>>(Cpart, o1b1, H1);
  k_gemm2<<<dim3(64, 12), 256, 0, stream>>>(H1, o1w2, o1b2, O1);
  k_reg2<<<B_, 192, 0, stream>>>(O1, xin, r2w1, r2b1, r2w2, r2b2, out);
}